// Round 3
// baseline (696.381 us; speedup 1.0000x reference)
//
#include <hip/hip_runtime.h>
#include <math.h>

typedef unsigned short u16;
typedef __attribute__((ext_vector_type(8))) short short8;
typedef __attribute__((ext_vector_type(4))) float f32x4;

#define PBSTR ((long)16382 * 24)
#define PFSTR ((long)15360 * 24)

__device__ __forceinline__ u16 f2bf(float f) {
    unsigned u = __float_as_uint(f);
    unsigned r = u + 0x7FFFu + ((u >> 16) & 1u);
    return (u16)(r >> 16);
}
__device__ __forceinline__ float bf2f(u16 v) { return __uint_as_float((unsigned)v << 16); }
__device__ __forceinline__ unsigned pk2(float a, float b) {
    return (unsigned)f2bf(a) | ((unsigned)f2bf(b) << 16);
}
__device__ __forceinline__ float sigf(float x) { return 1.f / (1.f + __expf(-x)); }
__device__ __forceinline__ float tanhfast(float x) { return 2.f / (1.f + __expf(-2.f * x)) - 1.f; }

__device__ __forceinline__ short8 ldfrag(const u16* p) { return *(const short8*)p; }
__device__ __forceinline__ short8 ldfrag(const float* p) {
    float4 v0 = *(const float4*)p;
    float4 v1 = *(const float4*)(p + 4);
    union { uint4 u; short8 s; } cv;
    cv.u.x = pk2(v0.x, v0.y); cv.u.y = pk2(v0.z, v0.w);
    cv.u.z = pk2(v1.x, v1.y); cv.u.w = pk2(v1.z, v1.w);
    return cv.s;
}

// ---------------------------------------------------------------------------
__global__ __launch_bounds__(256) void build_gf_w(
    const float* __restrict__ cW, const float* __restrict__ cb,
    const float* __restrict__ gW, const float* __restrict__ gb,
    const float* __restrict__ fW, const float* __restrict__ fb,
    u16* __restrict__ Wt, float* __restrict__ biasGF)
{
    int idx = blockIdx.x * 256 + threadIdx.x;
    if (idx < 49152) {
        int nr = idx / 768, k = idx % 768, tau = k / 256, ci = k % 256;
        float val = 0.f;
        if (nr < 48) {
            const float* G = (nr < 24) ? gW : fW;
            int n = (nr < 24) ? nr : nr - 24;
            auto dotf = [&](int i, int j) {
                const float* a = cW + i * 65536 + ci * 256;
                const float* g = G + j * 6144 + n;
                float s = 0.f;
                for (int o = 0; o < 256; ++o) s += a[o] * g[o * 24];
                return s;
            };
            if (tau == 0)      val = dotf(0, 0);
            else if (tau == 1) val = dotf(0, 1) + dotf(1, 0);
            else               val = dotf(1, 1);
        }
        Wt[idx] = f2bf(val);
    }
    if (blockIdx.x == 0 && threadIdx.x < 48) {
        int nr = threadIdx.x;
        const float* G = (nr < 24) ? gW : fW;
        const float* B = (nr < 24) ? gb : fb;
        int n = (nr < 24) ? nr : nr - 24;
        float s = B[n];
        for (int o = 0; o < 256; ++o) s += cb[o] * (G[o * 24 + n] + G[6144 + o * 24 + n]);
        biasGF[nr] = s;
    }
}

// bf16 MFMA weight tables for the gated stack:
//   Wgf: [9][48][64]  n<24 gate, n>=24 filter; k<24 tap0, 32<=k<56 tap1, rest 0
//   Wsc: [9][32][32]  B[n][k] = scale_W[i][0][k][n], zero-padded
__global__ __launch_bounds__(256) void build_wt_misc(
    const float* __restrict__ f1W, const float* __restrict__ f2W,
    const float* __restrict__ resW8,
    const float* __restrict__ gateW, const float* __restrict__ filtW,
    const float* __restrict__ sclW,
    u16* __restrict__ Wt1, u16* __restrict__ Wt2, u16* __restrict__ Wtr,
    u16* __restrict__ Wgf, u16* __restrict__ Wsc)
{
    int idx = blockIdx.x * 256 + threadIdx.x;
    if (idx < 32768) {
        int n = idx / 128, k = idx % 128;
        Wt1[idx] = f2bf(f1W[k * 256 + n]);
    } else if (idx < 98304) {
        int j = idx - 32768; int n = j / 256, k = j % 256;
        Wt2[j] = f2bf(f2W[k * 256 + n]);
    } else if (idx < 102400) {
        int j = idx - 98304; int n = j / 32, k = j % 32;
        Wtr[j] = (k < 24) ? f2bf(resW8[k * 128 + n]) : (u16)0;
    } else if (idx < 130048) {
        int j = idx - 102400;
        int i = j / 3072, r = (j % 3072) / 64, k = j % 64;
        float v = 0.f;
        int tap = -1, ci = 0;
        if (k < 24) { tap = 0; ci = k; }
        else if (k >= 32 && k < 56) { tap = 1; ci = k - 32; }
        if (tap >= 0) {
            const float* W = (r < 24) ? gateW : filtW;
            int co = (r < 24) ? r : r - 24;
            v = W[((i * 2 + tap) * 24 + ci) * 24 + co];
        }
        Wgf[j] = f2bf(v);
    } else if (idx < 139264) {
        int j = idx - 130048;
        int i = j / 1024, r = (j % 1024) / 32, k = j % 32;
        float v = (r < 24 && k < 24) ? sclW[(i * 24 + k) * 24 + r] : 0.f;
        Wsc[j] = f2bf(v);
    }
}

// ---------------------------------------------------------------------------
template<typename AT, int KTOT, int NTILES, int ACT>
__global__ __launch_bounds__(256) void gemm_bstat(
    const AT* __restrict__ A, long A_bstride, int A_rs,
    const u16* __restrict__ Wt, int Wt_rs,
    const float* __restrict__ bias,
    u16* __restrict__ C, long C_bstride, int C_rs, int L_out)
{
    constexpr int BS = KTOT + 8;
    constexpr int NROWS = NTILES * 16;
    constexpr int KS = KTOT / 32;
    __shared__ __align__(16) u16 Bs[NROWS * BS];
    __shared__ float biasL[NROWS];
    const int tid = threadIdx.x;
    const int n0 = blockIdx.y * NROWS;

    for (int i = tid; i < NROWS * (KTOT / 8); i += 256) {
        int rn = i / (KTOT / 8), kk = i % (KTOT / 8);
        *(uint4*)&Bs[rn * BS + kk * 8] = *(const uint4*)(Wt + (long)(n0 + rn) * Wt_rs + kk * 8);
    }
    if (tid < NROWS) biasL[tid] = bias[n0 + tid];

    const int wv = tid >> 6, lane = tid & 63, col = lane & 15, quad = lane >> 4;
    const int b = blockIdx.z;
    const int m0 = blockIdx.x * 128 + wv * 32;
    const AT* Ab = A + (long)b * A_bstride;
    const int rmax = L_out - 1;

    short8 afr[KS][2];
#pragma unroll
    for (int ks = 0; ks < KS; ++ks)
#pragma unroll
        for (int mt = 0; mt < 2; ++mt) {
            int r = m0 + mt * 16 + col;
            if (r > rmax) r = rmax;
            afr[ks][mt] = ldfrag(Ab + (long)r * A_rs + ks * 32 + quad * 8);
        }

    f32x4 acc[2][NTILES];
#pragma unroll
    for (int i = 0; i < 2; ++i)
#pragma unroll
        for (int j = 0; j < NTILES; ++j) acc[i][j] = (f32x4){0.f, 0.f, 0.f, 0.f};

    __syncthreads();

#pragma unroll
    for (int ks = 0; ks < KS; ++ks) {
#pragma unroll
        for (int nt = 0; nt < NTILES; ++nt) {
            short8 bb = *(const short8*)&Bs[(nt * 16 + col) * BS + ks * 32 + quad * 8];
            acc[0][nt] = __builtin_amdgcn_mfma_f32_16x16x32_bf16(afr[ks][0], bb, acc[0][nt], 0, 0, 0);
            acc[1][nt] = __builtin_amdgcn_mfma_f32_16x16x32_bf16(afr[ks][1], bb, acc[1][nt], 0, 0, 0);
        }
    }

#pragma unroll
    for (int mt = 0; mt < 2; ++mt)
#pragma unroll
        for (int nt = 0; nt < NTILES; ++nt)
#pragma unroll
            for (int rr = 0; rr < 4; ++rr) {
                int t = m0 + mt * 16 + quad * 4 + rr;
                if (t < L_out) {
                    float v = acc[mt][nt][rr] + biasL[nt * 16 + col];
                    if (ACT == 1) v = fmaxf(v, 0.f);
                    C[(long)b * C_bstride + (long)t * C_rs + n0 + nt * 16 + col] = f2bf(v);
                }
            }
}

// ---------------------------------------------------------------------------
// v5: v3 structure (prefetch reverted — it regressed), bf16 P output.
__global__ __launch_bounds__(256) void gf_fused_v5(
    const float* __restrict__ x, const u16* __restrict__ Wt,
    const float* __restrict__ biasGF,
    const float* __restrict__ sW, const float* __restrict__ sb,
    u16* __restrict__ P)
{
    __shared__ __align__(16) union {
        u16 bs[48 * 392];
        struct { float pre[128 * 49]; float h[128 * 24]; } ep;
    } U;
    __shared__ float WsT[24 * 28];
    __shared__ float biasL[48];
    __shared__ float sbL[24];

    const int tid = threadIdx.x;
    const int m0 = blockIdx.x * 128;
    const int b = blockIdx.z;
    const float* xb = x + (long)b * (16384 * 256);
    const int L = 16382;

    for (int i = tid; i < 576; i += 256) { int c = i / 24, n = i % 24; WsT[n * 28 + c] = sW[i]; }
    if (tid < 48) biasL[tid] = biasGF[tid];
    if (tid < 24) sbL[tid] = sb[tid];

    const int wv = tid >> 6, lane = tid & 63, col = lane & 15, quad = lane >> 4;

    f32x4 acc[2][3];
#pragma unroll
    for (int i = 0; i < 2; ++i)
#pragma unroll
        for (int j = 0; j < 3; ++j) acc[i][j] = (f32x4){0.f, 0.f, 0.f, 0.f};

    for (int half = 0; half < 2; ++half) {
        if (half) __syncthreads();
        for (int i = tid; i < 2304; i += 256) {
            int rn = i / 48, kk = i % 48;
            *(uint4*)&U.bs[rn * 392 + kk * 8] =
                *(const uint4*)(Wt + (long)rn * 768 + half * 384 + kk * 8);
        }
        __syncthreads();

        for (int k0 = 0; k0 < 384; k0 += 32) {
            short8 a[2];
#pragma unroll
            for (int mt = 0; mt < 2; ++mt) {
                int g = m0 + wv * 32 + mt * 16 + col;
                if (g > 16381) g = 16381;
                a[mt] = ldfrag(xb + (long)g * 256 + half * 384 + k0 + quad * 8);
            }
#pragma unroll
            for (int nt = 0; nt < 3; ++nt) {
                short8 bb = *(const short8*)&U.bs[(nt * 16 + col) * 392 + k0 + quad * 8];
                acc[0][nt] = __builtin_amdgcn_mfma_f32_16x16x32_bf16(a[0], bb, acc[0][nt], 0, 0, 0);
                acc[1][nt] = __builtin_amdgcn_mfma_f32_16x16x32_bf16(a[1], bb, acc[1][nt], 0, 0, 0);
            }
        }
    }

    __syncthreads();
#pragma unroll
    for (int mt = 0; mt < 2; ++mt)
#pragma unroll
        for (int nt = 0; nt < 3; ++nt)
#pragma unroll
            for (int rr = 0; rr < 4; ++rr) {
                int lrow = wv * 32 + mt * 16 + quad * 4 + rr;
                int c = nt * 16 + col;
                U.ep.pre[lrow * 49 + c] = acc[mt][nt][rr] + biasL[c];
            }
    __syncthreads();
    for (int i = tid; i < 3072; i += 256) {
        int t = i / 24, c = i - t * 24;
        U.ep.h[t * 24 + c] = sigf(U.ep.pre[t * 49 + c]) * tanhfast(U.ep.pre[t * 49 + 24 + c]);
    }
    __syncthreads();
    {
        int t = tid >> 1, half = tid & 1;
        float hv[24];
#pragma unroll
        for (int q = 0; q < 6; ++q) {
            float4 v = *(const float4*)&U.ep.h[t * 24 + q * 4];
            hv[q * 4] = v.x; hv[q * 4 + 1] = v.y; hv[q * 4 + 2] = v.z; hv[q * 4 + 3] = v.w;
        }
        if (m0 + t < L) {
#pragma unroll
            for (int j = 0; j < 12; ++j) {
                int n = half * 12 + j;
                float o = sbL[n];
#pragma unroll
                for (int q = 0; q < 6; ++q) {
                    float4 w = *(const float4*)&WsT[n * 28 + q * 4];
                    o += hv[q*4] * w.x + hv[q*4+1] * w.y + hv[q*4+2] * w.z + hv[q*4+3] * w.w;
                }
                P[(long)b * PBSTR + (long)(m0 + t) * 24 + n] = f2bf(o);
            }
        }
    }
}

// ---------------------------------------------------------------------------
// All 9 dilated gated layers fused in one kernel via halo recomputation.
// Block owns 256 final rows; window = 1278 input rows held in LDS (bf16,
// stride 24); layers applied in place, chunk-ordered (out[t] reads only
// rows >= t). g/f pairing in-register via shfl_xor(.,8); 1 barrier/chunk
// (double-buffered h scratch bounds wave skew to <2 chunks).
__global__ __launch_bounds__(256) void gated_stack(
    const u16* __restrict__ P0,
    const u16* __restrict__ WgfG, const u16* __restrict__ WsG,
    const float* __restrict__ gateB, const float* __restrict__ filtB,
    const float* __restrict__ sclB,
    u16* __restrict__ Pfin)
{
    __shared__ __align__(16) u16 buf[1296 * 24];   // 62208 B
    __shared__ __align__(16) u16 hs[2][64 * 40];   // 10240 B

    const int tid = threadIdx.x;
    const int wv = tid >> 6, lane = tid & 63, col = lane & 15, quad = lane >> 4;
    const int m0 = blockIdx.x * 256;
    const int b  = blockIdx.z;

    {   // stage window [m0, m0+1278); zero pad rows 1278..1295
        const u16* src = P0 + (long)b * PBSTR + (long)m0 * 24;
        for (int j = tid; j < 3888; j += 256) {
            uint4 v = (j < 3834) ? *(const uint4*)(src + j * 8) : (uint4){0, 0, 0, 0};
            *(uint4*)&buf[j * 8] = v;
        }
    }
    if (tid < 128) {   // zero h-scratch pad ch 24..31 (both buffers)
        int bu = tid >> 6, r = tid & 63;
        *(uint4*)&hs[bu][r * 40 + 24] = (uint4){0, 0, 0, 0};
    }
    __syncthreads();

    int W = 1278;
    int hb = 0;
    for (int li = 0; li < 9; ++li) {
        const int d = 2 << li;
        const int Wn = W - d;
        const bool last = (li == 8);

        // hoist weight fragments from global (L2-hot, once per layer)
        const u16* wg = WgfG + li * 3072;
        short8 bgf0[3], bgf1[3];
#pragma unroll
        for (int nt = 0; nt < 3; ++nt) {
            bgf0[nt] = *(const short8*)(wg + (nt * 16 + col) * 64 + quad * 8);
            bgf1[nt] = *(const short8*)(wg + (nt * 16 + col) * 64 + 32 + quad * 8);
        }
        const u16* wsp = WsG + li * 1024;
        short8 wsf0 = *(const short8*)(wsp + col * 32 + quad * 8);
        short8 wsf1 = *(const short8*)(wsp + (16 + col) * 32 + quad * 8);
        const float bv0 = gateB[li * 24 + col];
        const float bv1 = (col < 8) ? gateB[li * 24 + 16 + col] : filtB[li * 24 + col - 8];
        const float bv2 = filtB[li * 24 + 8 + col];
        const float sv0 = sclB[li * 24 + col];
        const float sv1 = (col < 8) ? sclB[li * 24 + 16 + col] : 0.f;

        for (int c = 0; c < Wn; c += 64) {
            // ---- phase 1: g/f conv + activation -> h scratch
            const int r0 = c + wv * 16 + col;
            short8 a0 = *(const short8*)&buf[r0 * 24 + quad * 8];
            short8 a1 = *(const short8*)&buf[(r0 + d) * 24 + quad * 8];
            f32x4 ac0 = {0.f, 0.f, 0.f, 0.f}, ac1 = ac0, ac2 = ac0;
            ac0 = __builtin_amdgcn_mfma_f32_16x16x32_bf16(a0, bgf0[0], ac0, 0, 0, 0);
            ac0 = __builtin_amdgcn_mfma_f32_16x16x32_bf16(a1, bgf1[0], ac0, 0, 0, 0);
            ac1 = __builtin_amdgcn_mfma_f32_16x16x32_bf16(a0, bgf0[1], ac1, 0, 0, 0);
            ac1 = __builtin_amdgcn_mfma_f32_16x16x32_bf16(a1, bgf1[1], ac1, 0, 0, 0);
            ac2 = __builtin_amdgcn_mfma_f32_16x16x32_bf16(a0, bgf0[2], ac2, 0, 0, 0);
            ac2 = __builtin_amdgcn_mfma_f32_16x16x32_bf16(a1, bgf1[2], ac2, 0, 0, 0);

            const int lr = wv * 16 + quad * 4;
            u16* hp = &hs[hb][0];
#pragma unroll
            for (int rr = 0; rr < 4; ++rr) {
                float g0 = ac0[rr] + bv0;   // pre ch col
                float m1 = ac1[rr] + bv1;   // pre ch 16+col
                float m2 = ac2[rr] + bv2;   // pre ch 32+col
                float s1 = __shfl_xor(m1, 8);
                float s2 = __shfl_xor(m2, 8);
                float f0 = (col < 8) ? s1 : s2;           // pre ch col+24
                hp[(lr + rr) * 40 + col] = f2bf(sigf(g0) * tanhfast(f0));
                if (col < 8)                               // h ch 16+col
                    hp[(lr + rr) * 40 + 16 + col] = f2bf(sigf(m1) * tanhfast(s2));
            }
            __syncthreads();

            // ---- phase 2: 1x1 scale conv + residual(last) -> write in place
            short8 aH = *(const short8*)&hp[(wv * 16 + col) * 40 + quad * 8];
            f32x4 c0 = {0.f, 0.f, 0.f, 0.f}, c1 = c0;
            c0 = __builtin_amdgcn_mfma_f32_16x16x32_bf16(aH, wsf0, c0, 0, 0, 0);
            c1 = __builtin_amdgcn_mfma_f32_16x16x32_bf16(aH, wsf1, c1, 0, 0, 0);
#pragma unroll
            for (int rr = 0; rr < 4; ++rr) {
                int t = c + wv * 16 + quad * 4 + rr;
                float v0 = c0[rr] + sv0;
                if (last) v0 += bf2f(buf[(t + 256) * 24 + col]);
                buf[t * 24 + col] = f2bf(v0);
                if (col < 8) {
                    float v1 = c1[rr] + sv1;
                    if (last) v1 += bf2f(buf[(t + 256) * 24 + 16 + col]);
                    buf[t * 24 + 16 + col] = f2bf(v1);
                }
            }
            hb ^= 1;
        }
        __syncthreads();
        W = Wn;
    }

    {   // copy out rows [0,256) -> Pfin
        u16* dst = Pfin + (long)b * PFSTR + (long)m0 * 24;
        for (int j = tid; j < 768; j += 256)
            *(uint4*)(dst + j * 8) = *(const uint4*)&buf[j * 8];
    }
}

// ---------------------------------------------------------------------------
__global__ __launch_bounds__(256) void f2_softmax_v2(
    const u16* __restrict__ A, const u16* __restrict__ Wt2,
    const float* __restrict__ bias, float* __restrict__ out)
{
    __shared__ __align__(16) u16 Bs[2][256 * 40];
    __shared__ float biasL[256];
    const int tid = threadIdx.x;
    const int b = blockIdx.y;
    const int t0 = blockIdx.x * 64;
    biasL[tid] = bias[tid];

    const int wv = tid >> 6, lane = tid & 63, col = lane & 15, quad = lane >> 4;
    const u16* Ab = A + (long)b * (15360L * 256);
    const int row = t0 + wv * 16 + col;

    auto stage = [&](int kc, int buf) {
#pragma unroll
        for (int j = 0; j < 4; ++j) {
            int idx = tid * 4 + j;
            int rn = idx >> 2, kk = idx & 3;
            *(uint4*)&Bs[buf][rn * 40 + kk * 8] =
                *(const uint4*)(Wt2 + (long)rn * 256 + kc * 32 + kk * 8);
        }
    };

    short8 afr[8];
#pragma unroll
    for (int kc = 0; kc < 8; ++kc)
        afr[kc] = *(const short8*)(Ab + (long)row * 256 + kc * 32 + quad * 8);

    f32x4 acc[16];
#pragma unroll
    for (int i = 0; i < 16; ++i) acc[i] = (f32x4){0.f, 0.f, 0.f, 0.f};

    stage(0, 0);
    __syncthreads();
    for (int kc = 0; kc < 8; ++kc) {
        int buf = kc & 1;
        if (kc < 7) stage(kc + 1, buf ^ 1);
#pragma unroll
        for (int nt = 0; nt < 16; ++nt) {
            short8 bb = *(const short8*)&Bs[buf][(nt * 16 + col) * 40 + quad * 8];
            acc[nt] = __builtin_amdgcn_mfma_f32_16x16x32_bf16(afr[kc], bb, acc[nt], 0, 0, 0);
        }
        __syncthreads();
    }

#pragma unroll
    for (int r = 0; r < 4; ++r) {
        int tl = wv * 16 + quad * 4 + r;
        float v[16];
        float m = -1e30f;
#pragma unroll
        for (int nt = 0; nt < 16; ++nt) {
            v[nt] = acc[nt][r] + biasL[nt * 16 + col];
            m = fmaxf(m, v[nt]);
        }
        m = fmaxf(m, __shfl_xor(m, 1));
        m = fmaxf(m, __shfl_xor(m, 2));
        m = fmaxf(m, __shfl_xor(m, 4));
        m = fmaxf(m, __shfl_xor(m, 8));
        float s = 0.f;
#pragma unroll
        for (int nt = 0; nt < 16; ++nt) { v[nt] = __expf(v[nt] - m); s += v[nt]; }
        s += __shfl_xor(s, 1);
        s += __shfl_xor(s, 2);
        s += __shfl_xor(s, 4);
        s += __shfl_xor(s, 8);
        float inv = 1.f / s;
        float* op = out + ((long)b * 15360 + t0 + tl) * 256;
#pragma unroll
        for (int nt = 0; nt < 16; ++nt) op[nt * 16 + col] = v[nt] * inv;
    }
}

// ---------------------------------------------------------------------------
extern "C" void kernel_launch(void* const* d_in, const int* in_sizes, int n_in,
                              void* d_out, int out_size, void* d_ws, size_t ws_size,
                              hipStream_t stream)
{
    const float* x        = (const float*)d_in[0];
    const float* causal_W = (const float*)d_in[1];
    const float* causal_b = (const float*)d_in[2];
    const float* gW0      = (const float*)d_in[3];
    const float* gb0      = (const float*)d_in[4];
    const float* fW0      = (const float*)d_in[5];
    const float* fb0      = (const float*)d_in[6];
    const float* sW0      = (const float*)d_in[7];
    const float* sb0      = (const float*)d_in[8];
    const float* gate_W   = (const float*)d_in[9];
    const float* gate_b   = (const float*)d_in[10];
    const float* filter_W = (const float*)d_in[11];
    const float* filter_b = (const float*)d_in[12];
    const float* scale_W  = (const float*)d_in[13];
    const float* scale_b  = (const float*)d_in[14];
    const float* res_W    = (const float*)d_in[15];
    const float* res_b    = (const float*)d_in[16];
    const float* f1_W     = (const float*)d_in[17];
    const float* f1_b     = (const float*)d_in[18];
    const float* f2_W     = (const float*)d_in[19];
    const float* f2_b     = (const float*)d_in[20];

    char* w = (char*)d_ws;
    u16* ACC  = (u16*)w;   w += (size_t)8 * 15360 * 128 * 2;
    u16* A1   = (u16*)w;   w += (size_t)8 * 15360 * 256 * 2;
    u16* P0   = (u16*)w;   w += (size_t)8 * 16382 * 24 * 2;
    u16* Pfin = (u16*)w;   w += (size_t)8 * 15360 * 24 * 2 + 128;
    u16* WtGF = (u16*)w;   w += (size_t)64 * 768 * 2;
    u16* Wt1  = (u16*)w;   w += (size_t)256 * 128 * 2;
    u16* Wt2  = (u16*)w;   w += (size_t)256 * 256 * 2;
    u16* Wtr  = (u16*)w;   w += (size_t)128 * 32 * 2;
    float* biasGF = (float*)w; w += 256;
    u16* WgfG = (u16*)w;   w += (size_t)9 * 48 * 64 * 2;
    u16* WsG  = (u16*)w;   w += (size_t)9 * 32 * 32 * 2;

    dim3 blk(256);

    build_gf_w<<<dim3(192), blk, 0, stream>>>(causal_W, causal_b, gW0, gb0, fW0, fb0,
                                              WtGF, biasGF);
    build_wt_misc<<<dim3(544), blk, 0, stream>>>(f1_W, f2_W, res_W + (size_t)8 * 24 * 128,
                                                 gate_W, filter_W, scale_W,
                                                 Wt1, Wt2, Wtr, WgfG, WsG);

    gf_fused_v5<<<dim3(128, 1, 8), blk, 0, stream>>>(x, WtGF, biasGF, sW0, sb0, P0);

    gated_stack<<<dim3(60, 1, 8), blk, 0, stream>>>(P0, WgfG, WsG,
                                                    gate_b, filter_b, scale_b, Pfin);

    gemm_bstat<u16, 32, 8, 1><<<dim3(120, 1, 8), blk, 0, stream>>>(
        Pfin, PFSTR, 24, Wtr, 32, res_b + 8 * 128,
        ACC, (long)15360 * 128, 128, 15360);

    gemm_bstat<u16, 128, 8, 1><<<dim3(120, 2, 8), blk, 0, stream>>>(
        ACC, (long)15360 * 128, 128, Wt1, 128, f1_b,
        A1, (long)15360 * 256, 256, 15360);

    f2_softmax_v2<<<dim3(240, 8), blk, 0, stream>>>(A1, Wt2, f2_b, (float*)d_out);
}

// Round 4
// 557.331 us; speedup vs baseline: 1.2495x; 1.2495x over previous
//
#include <hip/hip_runtime.h>
#include <math.h>

typedef unsigned short u16;
typedef __attribute__((ext_vector_type(8))) short short8;
typedef __attribute__((ext_vector_type(4))) float f32x4;

#define PBSTR ((long)16382 * 24)

__device__ __forceinline__ u16 f2bf(float f) {
    unsigned u = __float_as_uint(f);
    unsigned r = u + 0x7FFFu + ((u >> 16) & 1u);
    return (u16)(r >> 16);
}
__device__ __forceinline__ float bf2f(u16 v) { return __uint_as_float((unsigned)v << 16); }
__device__ __forceinline__ unsigned pk2(float a, float b) {
    return (unsigned)f2bf(a) | ((unsigned)f2bf(b) << 16);
}
__device__ __forceinline__ float sigf(float x) { return 1.f / (1.f + __expf(-x)); }
__device__ __forceinline__ float tanhfast(float x) { return 2.f / (1.f + __expf(-2.f * x)) - 1.f; }

__device__ __forceinline__ short8 ldfrag(const u16* p) { return *(const short8*)p; }
__device__ __forceinline__ short8 ldfrag(const float* p) {
    float4 v0 = *(const float4*)p;
    float4 v1 = *(const float4*)(p + 4);
    union { uint4 u; short8 s; } cv;
    cv.u.x = pk2(v0.x, v0.y); cv.u.y = pk2(v0.z, v0.w);
    cv.u.z = pk2(v1.x, v1.y); cv.u.w = pk2(v1.z, v1.w);
    return cv.s;
}

// ---------------------------------------------------------------------------
// All weight-table builds in ONE launch.
//   blocks [0,192):   Wt (gf fused first-layer weights) + biasGF
//   blocks [192,736): Wt1 / Wt2 / Wtr / Wgf / Wsc
__global__ __launch_bounds__(256) void build_all(
    const float* __restrict__ cW, const float* __restrict__ cb,
    const float* __restrict__ gW, const float* __restrict__ gb,
    const float* __restrict__ fW, const float* __restrict__ fb,
    u16* __restrict__ Wt, float* __restrict__ biasGF,
    const float* __restrict__ f1W, const float* __restrict__ f2W,
    const float* __restrict__ resW8,
    const float* __restrict__ gateW, const float* __restrict__ filtW,
    const float* __restrict__ sclW,
    u16* __restrict__ Wt1, u16* __restrict__ Wt2, u16* __restrict__ Wtr,
    u16* __restrict__ Wgf, u16* __restrict__ Wsc)
{
    if (blockIdx.x < 192) {
        int idx = blockIdx.x * 256 + threadIdx.x;
        if (idx < 49152) {
            int nr = idx / 768, k = idx % 768, tau = k / 256, ci = k % 256;
            float val = 0.f;
            if (nr < 48) {
                const float* G = (nr < 24) ? gW : fW;
                int n = (nr < 24) ? nr : nr - 24;
                auto dotf = [&](int i, int j) {
                    const float* a = cW + i * 65536 + ci * 256;
                    const float* g = G + j * 6144 + n;
                    float s = 0.f;
                    for (int o = 0; o < 256; o += 4) {
                        float4 av = *(const float4*)(a + o);
                        const float* gp = g + o * 24;
                        s += av.x * gp[0] + av.y * gp[24] + av.z * gp[48] + av.w * gp[72];
                    }
                    return s;
                };
                if (tau == 0)      val = dotf(0, 0);
                else if (tau == 1) val = dotf(0, 1) + dotf(1, 0);
                else               val = dotf(1, 1);
            }
            Wt[idx] = f2bf(val);
        }
        if (blockIdx.x == 0 && threadIdx.x < 48) {
            int nr = threadIdx.x;
            const float* G = (nr < 24) ? gW : fW;
            const float* B = (nr < 24) ? gb : fb;
            int n = (nr < 24) ? nr : nr - 24;
            float s = B[n];
            for (int o = 0; o < 256; ++o) s += cb[o] * (G[o * 24 + n] + G[6144 + o * 24 + n]);
            biasGF[nr] = s;
        }
    } else {
        int idx = (blockIdx.x - 192) * 256 + threadIdx.x;
        if (idx < 32768) {
            int n = idx / 128, k = idx % 128;
            Wt1[idx] = f2bf(f1W[k * 256 + n]);
        } else if (idx < 98304) {
            int j = idx - 32768; int n = j / 256, k = j % 256;
            Wt2[j] = f2bf(f2W[k * 256 + n]);
        } else if (idx < 102400) {
            int j = idx - 98304; int n = j / 32, k = j % 32;
            Wtr[j] = (k < 24) ? f2bf(resW8[k * 128 + n]) : (u16)0;
        } else if (idx < 130048) {
            int j = idx - 102400;
            int i = j / 3072, r = (j % 3072) / 64, k = j % 64;
            float v = 0.f;
            int tap = -1, ci = 0;
            if (k < 24) { tap = 0; ci = k; }
            else if (k >= 32 && k < 56) { tap = 1; ci = k - 32; }
            if (tap >= 0) {
                const float* W = (r < 24) ? gateW : filtW;
                int co = (r < 24) ? r : r - 24;
                v = W[((i * 2 + tap) * 24 + ci) * 24 + co];
            }
            Wgf[j] = f2bf(v);
        } else if (idx < 139264) {
            int j = idx - 130048;
            int i = j / 1024, r = (j % 1024) / 32, k = j % 32;
            float v = (r < 24 && k < 24) ? sclW[(i * 24 + k) * 24 + r] : 0.f;
            Wsc[j] = f2bf(v);
        }
    }
}

// ---------------------------------------------------------------------------
// v5: K-split weight staging, bf16 P output (unchanged from R3).
__global__ __launch_bounds__(256) void gf_fused_v5(
    const float* __restrict__ x, const u16* __restrict__ Wt,
    const float* __restrict__ biasGF,
    const float* __restrict__ sW, const float* __restrict__ sb,
    u16* __restrict__ P)
{
    __shared__ __align__(16) union {
        u16 bs[48 * 392];
        struct { float pre[128 * 49]; float h[128 * 24]; } ep;
    } U;
    __shared__ float WsT[24 * 28];
    __shared__ float biasL[48];
    __shared__ float sbL[24];

    const int tid = threadIdx.x;
    const int m0 = blockIdx.x * 128;
    const int b = blockIdx.z;
    const float* xb = x + (long)b * (16384 * 256);
    const int L = 16382;

    for (int i = tid; i < 576; i += 256) { int c = i / 24, n = i % 24; WsT[n * 28 + c] = sW[i]; }
    if (tid < 48) biasL[tid] = biasGF[tid];
    if (tid < 24) sbL[tid] = sb[tid];

    const int wv = tid >> 6, lane = tid & 63, col = lane & 15, quad = lane >> 4;

    f32x4 acc[2][3];
#pragma unroll
    for (int i = 0; i < 2; ++i)
#pragma unroll
        for (int j = 0; j < 3; ++j) acc[i][j] = (f32x4){0.f, 0.f, 0.f, 0.f};

    for (int half = 0; half < 2; ++half) {
        if (half) __syncthreads();
        for (int i = tid; i < 2304; i += 256) {
            int rn = i / 48, kk = i % 48;
            *(uint4*)&U.bs[rn * 392 + kk * 8] =
                *(const uint4*)(Wt + (long)rn * 768 + half * 384 + kk * 8);
        }
        __syncthreads();

        for (int k0 = 0; k0 < 384; k0 += 32) {
            short8 a[2];
#pragma unroll
            for (int mt = 0; mt < 2; ++mt) {
                int g = m0 + wv * 32 + mt * 16 + col;
                if (g > 16381) g = 16381;
                a[mt] = ldfrag(xb + (long)g * 256 + half * 384 + k0 + quad * 8);
            }
#pragma unroll
            for (int nt = 0; nt < 3; ++nt) {
                short8 bb = *(const short8*)&U.bs[(nt * 16 + col) * 392 + k0 + quad * 8];
                acc[0][nt] = __builtin_amdgcn_mfma_f32_16x16x32_bf16(a[0], bb, acc[0][nt], 0, 0, 0);
                acc[1][nt] = __builtin_amdgcn_mfma_f32_16x16x32_bf16(a[1], bb, acc[1][nt], 0, 0, 0);
            }
        }
    }

    __syncthreads();
#pragma unroll
    for (int mt = 0; mt < 2; ++mt)
#pragma unroll
        for (int nt = 0; nt < 3; ++nt)
#pragma unroll
            for (int rr = 0; rr < 4; ++rr) {
                int lrow = wv * 32 + mt * 16 + quad * 4 + rr;
                int c = nt * 16 + col;
                U.ep.pre[lrow * 49 + c] = acc[mt][nt][rr] + biasL[c];
            }
    __syncthreads();
    for (int i = tid; i < 3072; i += 256) {
        int t = i / 24, c = i - t * 24;
        U.ep.h[t * 24 + c] = sigf(U.ep.pre[t * 49 + c]) * tanhfast(U.ep.pre[t * 49 + 24 + c]);
    }
    __syncthreads();
    {
        int t = tid >> 1, half = tid & 1;
        float hv[24];
#pragma unroll
        for (int q = 0; q < 6; ++q) {
            float4 v = *(const float4*)&U.ep.h[t * 24 + q * 4];
            hv[q * 4] = v.x; hv[q * 4 + 1] = v.y; hv[q * 4 + 2] = v.z; hv[q * 4 + 3] = v.w;
        }
        if (m0 + t < L) {
#pragma unroll
            for (int j = 0; j < 12; ++j) {
                int n = half * 12 + j;
                float o = sbL[n];
#pragma unroll
                for (int q = 0; q < 6; ++q) {
                    float4 w = *(const float4*)&WsT[n * 28 + q * 4];
                    o += hv[q*4] * w.x + hv[q*4+1] * w.y + hv[q*4+2] * w.z + hv[q*4+3] * w.w;
                }
                P[(long)b * PBSTR + (long)(m0 + t) * 24 + n] = f2bf(o);
            }
        }
    }
}

// ---------------------------------------------------------------------------
// Per-layer gated kernel v2: weights in registers (from L2), in-register
// g/f activation via shfl_xor(.,8) (validated in R3), LDS 14 KB.
__global__ __launch_bounds__(256) void gated_mfma_v2(
    const u16* __restrict__ Pin,
    const u16* __restrict__ wg,   // [48][64] this layer
    const u16* __restrict__ ws,   // [32][32] this layer
    const float* __restrict__ gB, const float* __restrict__ fB,
    const float* __restrict__ sB,
    u16* __restrict__ Q, int Lout, int d, int trimOff)
{
    __shared__ __align__(16) u16 T[64 * 72];   // 9216 B
    __shared__ __align__(16) u16 H[64 * 40];   // 5120 B

    const int tid = threadIdx.x;
    const int wv = tid >> 6, lane = tid & 63, col = lane & 15, quad = lane >> 4;
    const int m0 = blockIdx.x * 64;
    const int b = blockIdx.z;
    const u16* Pb = Pin + (long)b * PBSTR;

    if (tid < 128) {
        int r = tid & 63, tap = tid >> 6;
        int t = m0 + r; if (t > Lout - 1) t = Lout - 1;
        const u16* src = Pb + (long)(t + tap * d) * 24;
        u16* dst = &T[r * 72 + tap * 32];
        *(uint4*)(dst)      = *(const uint4*)(src);
        *(uint4*)(dst + 8)  = *(const uint4*)(src + 8);
        *(uint4*)(dst + 16) = *(const uint4*)(src + 16);
        *(uint4*)(dst + 24) = (uint4){0, 0, 0, 0};
    } else if (tid < 192) {
        int r = tid - 128;
        *(uint4*)&H[r * 40 + 24] = (uint4){0, 0, 0, 0};
    }

    // weight fragments + biases from global (L2-hot)
    short8 bgf0[3], bgf1[3];
#pragma unroll
    for (int nt = 0; nt < 3; ++nt) {
        bgf0[nt] = *(const short8*)(wg + (nt * 16 + col) * 64 + quad * 8);
        bgf1[nt] = *(const short8*)(wg + (nt * 16 + col) * 64 + 32 + quad * 8);
    }
    short8 wsf0 = *(const short8*)(ws + col * 32 + quad * 8);
    short8 wsf1 = *(const short8*)(ws + (16 + col) * 32 + quad * 8);
    const float bv0 = gB[col];
    const float bv1 = (col < 8) ? gB[16 + col] : fB[col - 8];
    const float bv2 = fB[8 + col];
    const float sv0 = sB[col];
    const float sv1 = (col < 8) ? sB[16 + col] : 0.f;

    __syncthreads();

    // phase 1: g/f conv + activation -> H (bf16)
    short8 a0 = *(const short8*)&T[(wv * 16 + col) * 72 + quad * 8];
    short8 a1 = *(const short8*)&T[(wv * 16 + col) * 72 + 32 + quad * 8];
    f32x4 ac0 = {0.f, 0.f, 0.f, 0.f}, ac1 = ac0, ac2 = ac0;
    ac0 = __builtin_amdgcn_mfma_f32_16x16x32_bf16(a0, bgf0[0], ac0, 0, 0, 0);
    ac0 = __builtin_amdgcn_mfma_f32_16x16x32_bf16(a1, bgf1[0], ac0, 0, 0, 0);
    ac1 = __builtin_amdgcn_mfma_f32_16x16x32_bf16(a0, bgf0[1], ac1, 0, 0, 0);
    ac1 = __builtin_amdgcn_mfma_f32_16x16x32_bf16(a1, bgf1[1], ac1, 0, 0, 0);
    ac2 = __builtin_amdgcn_mfma_f32_16x16x32_bf16(a0, bgf0[2], ac2, 0, 0, 0);
    ac2 = __builtin_amdgcn_mfma_f32_16x16x32_bf16(a1, bgf1[2], ac2, 0, 0, 0);

    const int lr = wv * 16 + quad * 4;
#pragma unroll
    for (int rr = 0; rr < 4; ++rr) {
        float g0 = ac0[rr] + bv0;   // pre ch col
        float m1 = ac1[rr] + bv1;   // pre ch 16+col (col<8) / filter b
        float m2 = ac2[rr] + bv2;   // pre ch 32+col
        float s1 = __shfl_xor(m1, 8);
        float s2 = __shfl_xor(m2, 8);
        float f0 = (col < 8) ? s1 : s2;            // pre ch col+24
        H[(lr + rr) * 40 + col] = f2bf(sigf(g0) * tanhfast(f0));
        if (col < 8)
            H[(lr + rr) * 40 + 16 + col] = f2bf(sigf(m1) * tanhfast(s2));
    }
    __syncthreads();

    // phase 2: 1x1 scale conv (+ trim residual on last layer)
    short8 aH = *(const short8*)&H[(wv * 16 + col) * 40 + quad * 8];
    f32x4 c0 = {0.f, 0.f, 0.f, 0.f}, c1 = c0;
    c0 = __builtin_amdgcn_mfma_f32_16x16x32_bf16(aH, wsf0, c0, 0, 0, 0);
    c1 = __builtin_amdgcn_mfma_f32_16x16x32_bf16(aH, wsf1, c1, 0, 0, 0);
#pragma unroll
    for (int rr = 0; rr < 4; ++rr) {
        int t = m0 + wv * 16 + quad * 4 + rr;
        if (t < Lout) {
            float v0 = c0[rr] + sv0;
            if (trimOff >= 0) v0 += bf2f(Pb[(long)(t + trimOff) * 24 + col]);
            Q[(long)b * PBSTR + (long)t * 24 + col] = f2bf(v0);
            if (col < 8) {
                float v1 = c1[rr] + sv1;
                if (trimOff >= 0) v1 += bf2f(Pb[(long)(t + trimOff) * 24 + 16 + col]);
                Q[(long)b * PBSTR + (long)t * 24 + 16 + col] = f2bf(v1);
            }
        }
    }
}

// ---------------------------------------------------------------------------
// res-conv (K=24pad32 -> 128ch relu) + f1 (K=128 -> 256ch relu) fused.
// ACC tile lives in LDS between phases (kills the 63 MB HBM round trip).
// Grid: (120, 2 n-halves, 8).
__global__ __launch_bounds__(256) void res_f1_fused(
    const u16* __restrict__ Pfin,
    const u16* __restrict__ Wtr, const float* __restrict__ resb,
    const u16* __restrict__ Wt1, const float* __restrict__ f1b,
    u16* __restrict__ A1)
{
    __shared__ __align__(16) u16 ACCs[128 * 136];  // 34816 B
    __shared__ __align__(16) u16 W1s[128 * 136];   // 34816 B
    __shared__ float biasL[128];

    const int tid = threadIdx.x;
    const int wv = tid >> 6, lane = tid & 63, col = lane & 15, quad = lane >> 4;
    const int b = blockIdx.z;
    const int n0 = blockIdx.y * 128;
    const int m0 = blockIdx.x * 128;
    const u16* Pb = Pfin + (long)b * PBSTR;

    for (int i = tid; i < 2048; i += 256) {
        int rn = i >> 4, kk = i & 15;
        *(uint4*)&W1s[rn * 136 + kk * 8] = *(const uint4*)(Wt1 + (long)(n0 + rn) * 128 + kk * 8);
    }
    if (tid < 128) biasL[tid] = f1b[n0 + tid];

    // phase A: ACC = relu(Pfin x Wtr + resb) -> LDS bf16
    short8 bfr[8];
    float rbv[8];
#pragma unroll
    for (int nt = 0; nt < 8; ++nt) {
        bfr[nt] = *(const short8*)(Wtr + (nt * 16 + col) * 32 + quad * 8);
        rbv[nt] = resb[nt * 16 + col];
    }
    short8 afr[2];
#pragma unroll
    for (int mt = 0; mt < 2; ++mt) {
        int r = m0 + wv * 32 + mt * 16 + col;
        if (r > 15359) r = 15359;
        afr[mt] = *(const short8*)(Pb + (long)r * 24 + quad * 8);
    }
    f32x4 acc[2][8];
#pragma unroll
    for (int i = 0; i < 2; ++i)
#pragma unroll
        for (int j = 0; j < 8; ++j) acc[i][j] = (f32x4){0.f, 0.f, 0.f, 0.f};
#pragma unroll
    for (int nt = 0; nt < 8; ++nt) {
        acc[0][nt] = __builtin_amdgcn_mfma_f32_16x16x32_bf16(afr[0], bfr[nt], acc[0][nt], 0, 0, 0);
        acc[1][nt] = __builtin_amdgcn_mfma_f32_16x16x32_bf16(afr[1], bfr[nt], acc[1][nt], 0, 0, 0);
    }
#pragma unroll
    for (int mt = 0; mt < 2; ++mt)
#pragma unroll
        for (int nt = 0; nt < 8; ++nt)
#pragma unroll
            for (int rr = 0; rr < 4; ++rr) {
                int lrow = wv * 32 + mt * 16 + quad * 4 + rr;
                ACCs[lrow * 136 + nt * 16 + col] = f2bf(fmaxf(acc[mt][nt][rr] + rbv[nt], 0.f));
            }
    __syncthreads();

    // phase B: A1 = relu(ACC x Wt1^T + f1b)
    f32x4 acc2[2][8];
#pragma unroll
    for (int i = 0; i < 2; ++i)
#pragma unroll
        for (int j = 0; j < 8; ++j) acc2[i][j] = (f32x4){0.f, 0.f, 0.f, 0.f};
#pragma unroll
    for (int ks = 0; ks < 4; ++ks) {
        short8 am[2];
#pragma unroll
        for (int mt = 0; mt < 2; ++mt)
            am[mt] = *(const short8*)&ACCs[(wv * 32 + mt * 16 + col) * 136 + ks * 32 + quad * 8];
#pragma unroll
        for (int nt = 0; nt < 8; ++nt) {
            short8 bb = *(const short8*)&W1s[(nt * 16 + col) * 136 + ks * 32 + quad * 8];
            acc2[0][nt] = __builtin_amdgcn_mfma_f32_16x16x32_bf16(am[0], bb, acc2[0][nt], 0, 0, 0);
            acc2[1][nt] = __builtin_amdgcn_mfma_f32_16x16x32_bf16(am[1], bb, acc2[1][nt], 0, 0, 0);
        }
    }
#pragma unroll
    for (int mt = 0; mt < 2; ++mt)
#pragma unroll
        for (int nt = 0; nt < 8; ++nt)
#pragma unroll
            for (int rr = 0; rr < 4; ++rr) {
                int t = m0 + wv * 32 + mt * 16 + quad * 4 + rr;
                float v = fmaxf(acc2[mt][nt][rr] + biasL[nt * 16 + col], 0.f);
                A1[((long)b * 15360 + t) * 256 + n0 + nt * 16 + col] = f2bf(v);
            }
}

// ---------------------------------------------------------------------------
__global__ __launch_bounds__(256) void f2_softmax_v2(
    const u16* __restrict__ A, const u16* __restrict__ Wt2,
    const float* __restrict__ bias, float* __restrict__ out)
{
    __shared__ __align__(16) u16 Bs[2][256 * 40];
    __shared__ float biasL[256];
    const int tid = threadIdx.x;
    const int b = blockIdx.y;
    const int t0 = blockIdx.x * 64;
    biasL[tid] = bias[tid];

    const int wv = tid >> 6, lane = tid & 63, col = lane & 15, quad = lane >> 4;
    const u16* Ab = A + (long)b * (15360L * 256);
    const int row = t0 + wv * 16 + col;

    auto stage = [&](int kc, int buf) {
#pragma unroll
        for (int j = 0; j < 4; ++j) {
            int idx = tid * 4 + j;
            int rn = idx >> 2, kk = idx & 3;
            *(uint4*)&Bs[buf][rn * 40 + kk * 8] =
                *(const uint4*)(Wt2 + (long)rn * 256 + kc * 32 + kk * 8);
        }
    };

    short8 afr[8];
#pragma unroll
    for (int kc = 0; kc < 8; ++kc)
        afr[kc] = *(const short8*)(Ab + (long)row * 256 + kc * 32 + quad * 8);

    f32x4 acc[16];
#pragma unroll
    for (int i = 0; i < 16; ++i) acc[i] = (f32x4){0.f, 0.f, 0.f, 0.f};

    stage(0, 0);
    __syncthreads();
    for (int kc = 0; kc < 8; ++kc) {
        int buf = kc & 1;
        if (kc < 7) stage(kc + 1, buf ^ 1);
#pragma unroll
        for (int nt = 0; nt < 16; ++nt) {
            short8 bb = *(const short8*)&Bs[buf][(nt * 16 + col) * 40 + quad * 8];
            acc[nt] = __builtin_amdgcn_mfma_f32_16x16x32_bf16(afr[kc], bb, acc[nt], 0, 0, 0);
        }
        __syncthreads();
    }

#pragma unroll
    for (int r = 0; r < 4; ++r) {
        int tl = wv * 16 + quad * 4 + r;
        float v[16];
        float m = -1e30f;
#pragma unroll
        for (int nt = 0; nt < 16; ++nt) {
            v[nt] = acc[nt][r] + biasL[nt * 16 + col];
            m = fmaxf(m, v[nt]);
        }
        m = fmaxf(m, __shfl_xor(m, 1));
        m = fmaxf(m, __shfl_xor(m, 2));
        m = fmaxf(m, __shfl_xor(m, 4));
        m = fmaxf(m, __shfl_xor(m, 8));
        float s = 0.f;
#pragma unroll
        for (int nt = 0; nt < 16; ++nt) { v[nt] = __expf(v[nt] - m); s += v[nt]; }
        s += __shfl_xor(s, 1);
        s += __shfl_xor(s, 2);
        s += __shfl_xor(s, 4);
        s += __shfl_xor(s, 8);
        float inv = 1.f / s;
        float* op = out + ((long)b * 15360 + t0 + tl) * 256;
#pragma unroll
        for (int nt = 0; nt < 16; ++nt) op[nt * 16 + col] = v[nt] * inv;
    }
}

// ---------------------------------------------------------------------------
extern "C" void kernel_launch(void* const* d_in, const int* in_sizes, int n_in,
                              void* d_out, int out_size, void* d_ws, size_t ws_size,
                              hipStream_t stream)
{
    const float* x        = (const float*)d_in[0];
    const float* causal_W = (const float*)d_in[1];
    const float* causal_b = (const float*)d_in[2];
    const float* gW0      = (const float*)d_in[3];
    const float* gb0      = (const float*)d_in[4];
    const float* fW0      = (const float*)d_in[5];
    const float* fb0      = (const float*)d_in[6];
    const float* sW0      = (const float*)d_in[7];
    const float* sb0      = (const float*)d_in[8];
    const float* gate_W   = (const float*)d_in[9];
    const float* gate_b   = (const float*)d_in[10];
    const float* filter_W = (const float*)d_in[11];
    const float* filter_b = (const float*)d_in[12];
    const float* scale_W  = (const float*)d_in[13];
    const float* scale_b  = (const float*)d_in[14];
    const float* res_W    = (const float*)d_in[15];
    const float* res_b    = (const float*)d_in[16];
    const float* f1_W     = (const float*)d_in[17];
    const float* f1_b     = (const float*)d_in[18];
    const float* f2_W     = (const float*)d_in[19];
    const float* f2_b     = (const float*)d_in[20];

    char* w = (char*)d_ws;
    u16* A1   = (u16*)w;   w += (size_t)8 * 15360 * 256 * 2;
    u16* P0   = (u16*)w;   w += (size_t)8 * 16382 * 24 * 2 + 128;
    u16* P1   = (u16*)w;   w += (size_t)8 * 16382 * 24 * 2 + 128;
    u16* WtGF = (u16*)w;   w += (size_t)64 * 768 * 2;
    u16* Wt1  = (u16*)w;   w += (size_t)256 * 128 * 2;
    u16* Wt2  = (u16*)w;   w += (size_t)256 * 256 * 2;
    u16* Wtr  = (u16*)w;   w += (size_t)128 * 32 * 2;
    float* biasGF = (float*)w; w += 256;
    u16* WgfG = (u16*)w;   w += (size_t)9 * 48 * 64 * 2;
    u16* WsG  = (u16*)w;   w += (size_t)9 * 32 * 32 * 2;

    dim3 blk(256);

    build_all<<<dim3(736), blk, 0, stream>>>(
        causal_W, causal_b, gW0, gb0, fW0, fb0, WtGF, biasGF,
        f1_W, f2_W, res_W + (size_t)8 * 24 * 128,
        gate_W, filter_W, scale_W,
        Wt1, Wt2, Wtr, WgfG, WsG);

    gf_fused_v5<<<dim3(128, 1, 8), blk, 0, stream>>>(x, WtGF, biasGF, sW0, sb0, P0);

    u16* Pprev = P0;
    u16* Pnext = P1;
    int Lprev = 16382;
    for (int i = 0; i < 9; ++i) {
        int d = 2 << i;
        int L = Lprev - d;
        int trim = (i == 8) ? d / 2 : -1;
        gated_mfma_v2<<<dim3((L + 63) / 64, 1, 8), blk, 0, stream>>>(
            Pprev, WgfG + (size_t)i * 3072, WsG + (size_t)i * 1024,
            gate_b + i * 24, filter_b + i * 24, scale_b + i * 24,
            Pnext, L, d, trim);
        u16* tmp = Pprev; Pprev = Pnext; Pnext = tmp;
        Lprev = L;
    }

    res_f1_fused<<<dim3(120, 2, 8), blk, 0, stream>>>(
        Pprev, Wtr, res_b + 8 * 128, Wt1, f1_b, A1);

    f2_softmax_v2<<<dim3(240, 8), blk, 0, stream>>>(A1, Wt2, f2_b, (float*)d_out);
}

// Round 5
// 546.686 us; speedup vs baseline: 1.2738x; 1.0195x over previous
//
#include <hip/hip_runtime.h>
#include <math.h>

typedef unsigned short u16;
typedef __attribute__((ext_vector_type(8))) short short8;
typedef __attribute__((ext_vector_type(4))) float f32x4;

#define PBSTR ((long)16382 * 24)

__device__ __forceinline__ u16 f2bf(float f) {
    unsigned u = __float_as_uint(f);
    unsigned r = u + 0x7FFFu + ((u >> 16) & 1u);
    return (u16)(r >> 16);
}
__device__ __forceinline__ float bf2f(u16 v) { return __uint_as_float((unsigned)v << 16); }
__device__ __forceinline__ float sigf(float x) { return 1.f / (1.f + __expf(-x)); }
__device__ __forceinline__ float tanhfast(float x) { return 2.f / (1.f + __expf(-2.f * x)) - 1.f; }

// HW packed f32->bf16 (RNE, same rounding as f2bf): 1 instr per 2 values.
__device__ __forceinline__ unsigned cvtpk(float a, float b) {
    unsigned r;
    asm("v_cvt_pk_bf16_f32 %0, %1, %2" : "=v"(r) : "v"(a), "v"(b));
    return r;
}
__device__ __forceinline__ short8 ldfrag8(const float* p) {
    float4 v0 = *(const float4*)p;
    float4 v1 = *(const float4*)(p + 4);
    union { uint4 u; short8 s; } cv;
    cv.u.x = cvtpk(v0.x, v0.y); cv.u.y = cvtpk(v0.z, v0.w);
    cv.u.z = cvtpk(v1.x, v1.y); cv.u.w = cvtpk(v1.z, v1.w);
    return cv.s;
}

// ---------------------------------------------------------------------------
// All weight-table builds in ONE launch.
//   blocks [0,192):   Wt (gf fused first-layer weights) + biasGF
//   blocks [192,740): Wt1 / Wt2 / Wtr / Wgf / Wsc (10 slots: 9 layers + sW0)
__global__ __launch_bounds__(256) void build_all(
    const float* __restrict__ cW, const float* __restrict__ cb,
    const float* __restrict__ gW, const float* __restrict__ gb,
    const float* __restrict__ fW, const float* __restrict__ fb,
    u16* __restrict__ Wt, float* __restrict__ biasGF,
    const float* __restrict__ f1W, const float* __restrict__ f2W,
    const float* __restrict__ resW8,
    const float* __restrict__ gateW, const float* __restrict__ filtW,
    const float* __restrict__ sclW, const float* __restrict__ s0W,
    u16* __restrict__ Wt1, u16* __restrict__ Wt2, u16* __restrict__ Wtr,
    u16* __restrict__ Wgf, u16* __restrict__ Wsc)
{
    if (blockIdx.x < 192) {
        int idx = blockIdx.x * 256 + threadIdx.x;
        if (idx < 49152) {
            int nr = idx / 768, k = idx % 768, tau = k / 256, ci = k % 256;
            float val = 0.f;
            if (nr < 48) {
                const float* G = (nr < 24) ? gW : fW;
                int n = (nr < 24) ? nr : nr - 24;
                auto dotf = [&](int i, int j) {
                    const float* a = cW + i * 65536 + ci * 256;
                    const float* g = G + j * 6144 + n;
                    float s = 0.f;
                    for (int o = 0; o < 256; o += 4) {
                        float4 av = *(const float4*)(a + o);
                        const float* gp = g + o * 24;
                        s += av.x * gp[0] + av.y * gp[24] + av.z * gp[48] + av.w * gp[72];
                    }
                    return s;
                };
                if (tau == 0)      val = dotf(0, 0);
                else if (tau == 1) val = dotf(0, 1) + dotf(1, 0);
                else               val = dotf(1, 1);
            }
            Wt[idx] = f2bf(val);
        }
        if (blockIdx.x == 0 && threadIdx.x < 48) {
            int nr = threadIdx.x;
            const float* G = (nr < 24) ? gW : fW;
            const float* B = (nr < 24) ? gb : fb;
            int n = (nr < 24) ? nr : nr - 24;
            float s = B[n];
            for (int o = 0; o < 256; ++o) s += cb[o] * (G[o * 24 + n] + G[6144 + o * 24 + n]);
            biasGF[nr] = s;
        }
    } else {
        int idx = (blockIdx.x - 192) * 256 + threadIdx.x;
        if (idx < 32768) {
            int n = idx / 128, k = idx % 128;
            Wt1[idx] = f2bf(f1W[k * 256 + n]);
        } else if (idx < 98304) {
            int j = idx - 32768; int n = j / 256, k = j % 256;
            Wt2[j] = f2bf(f2W[k * 256 + n]);
        } else if (idx < 102400) {
            int j = idx - 98304; int n = j / 32, k = j % 32;
            Wtr[j] = (k < 24) ? f2bf(resW8[k * 128 + n]) : (u16)0;
        } else if (idx < 130048) {
            int j = idx - 102400;
            int i = j / 3072, r = (j % 3072) / 64, k = j % 64;
            float v = 0.f;
            int tap = -1, ci = 0;
            if (k < 24) { tap = 0; ci = k; }
            else if (k >= 32 && k < 56) { tap = 1; ci = k - 32; }
            if (tap >= 0) {
                const float* W = (r < 24) ? gateW : filtW;
                int co = (r < 24) ? r : r - 24;
                v = W[((i * 2 + tap) * 24 + ci) * 24 + co];
            }
            Wgf[j] = f2bf(v);
        } else if (idx < 140288) {
            int j = idx - 130048;
            int i = j / 1024, r = (j % 1024) / 32, k = j % 32;
            const float* S = (i < 9) ? (sclW + (size_t)i * 576) : s0W;
            float v = (r < 24 && k < 24) ? S[k * 24 + r] : 0.f;
            Wsc[j] = f2bf(v);
        }
    }
}

// ---------------------------------------------------------------------------
// v6: BM=256 (4 mtiles/wave), full-B single stage (74.5 KB, 2 blocks/CU),
// hardware cvt_pk for A conversion, shfl_xor in-register activation + MFMA
// s-conv epilogue (structure validated in gated_mfma_v2).
__global__ __launch_bounds__(256) void gf_fused_v6(
    const float* __restrict__ x, const u16* __restrict__ Wt,
    const float* __restrict__ biasGF,
    const u16* __restrict__ ws0, const float* __restrict__ sb,
    u16* __restrict__ P)
{
    __shared__ __align__(16) union {
        u16 bs[48 * 776];   // 74496 B
        u16 H[256 * 40];    // 20480 B
    } U;

    const int tid = threadIdx.x;
    const int m0 = blockIdx.x * 256;
    const int b = blockIdx.z;
    const float* xb = x + (long)b * (16384 * 256);

    for (int i = tid; i < 4608; i += 256) {
        int rn = i / 96, kk = i % 96;
        *(uint4*)&U.bs[rn * 776 + kk * 8] = *(const uint4*)(Wt + (long)rn * 768 + kk * 8);
    }

    const int wv = tid >> 6, lane = tid & 63, col = lane & 15, quad = lane >> 4;

    short8 wsf0 = *(const short8*)(ws0 + col * 32 + quad * 8);
    short8 wsf1 = *(const short8*)(ws0 + (16 + col) * 32 + quad * 8);
    const float bv0 = biasGF[col];
    const float bv1 = (col < 8) ? biasGF[16 + col] : biasGF[24 + col - 8];
    const float bv2 = biasGF[32 + col];
    const float sv0 = sb[col];
    const float sv1 = (col < 8) ? sb[16 + col] : 0.f;

    long rowoff[4];
#pragma unroll
    for (int mt = 0; mt < 4; ++mt) {
        int g = m0 + wv * 64 + mt * 16 + col;
        if (g > 16381) g = 16381;
        rowoff[mt] = (long)g * 256 + quad * 8;
    }

    f32x4 acc[4][3];
#pragma unroll
    for (int i = 0; i < 4; ++i)
#pragma unroll
        for (int j = 0; j < 3; ++j) acc[i][j] = (f32x4){0.f, 0.f, 0.f, 0.f};

    __syncthreads();

    for (int s = 0; s < 24; ++s) {
        short8 a[4];
#pragma unroll
        for (int mt = 0; mt < 4; ++mt)
            a[mt] = ldfrag8(xb + rowoff[mt] + s * 32);
#pragma unroll
        for (int nt = 0; nt < 3; ++nt) {
            short8 bb = *(const short8*)&U.bs[(nt * 16 + col) * 776 + s * 32 + quad * 8];
#pragma unroll
            for (int mt = 0; mt < 4; ++mt)
                acc[mt][nt] = __builtin_amdgcn_mfma_f32_16x16x32_bf16(a[mt], bb, acc[mt][nt], 0, 0, 0);
        }
    }

    __syncthreads();   // bs dead; reuse as H
    *(uint4*)&U.H[tid * 40 + 24] = (uint4){0, 0, 0, 0};   // zero K-pad ch 24..32

#pragma unroll
    for (int mt = 0; mt < 4; ++mt) {
        const int lr = wv * 64 + mt * 16 + quad * 4;
#pragma unroll
        for (int rr = 0; rr < 4; ++rr) {
            float g0 = acc[mt][0][rr] + bv0;   // pre ch col      (gate)
            float m1 = acc[mt][1][rr] + bv1;   // pre ch 16+col
            float m2 = acc[mt][2][rr] + bv2;   // pre ch 32+col
            float s1 = __shfl_xor(m1, 8);
            float s2 = __shfl_xor(m2, 8);
            float f0 = (col < 8) ? s1 : s2;    // pre ch col+24   (filter)
            U.H[(lr + rr) * 40 + col] = f2bf(sigf(g0) * tanhfast(f0));
            if (col < 8)
                U.H[(lr + rr) * 40 + 16 + col] = f2bf(sigf(m1) * tanhfast(s2));
        }
    }
    __syncthreads();

#pragma unroll
    for (int mt = 0; mt < 4; ++mt) {
        short8 aH = *(const short8*)&U.H[(wv * 64 + mt * 16 + col) * 40 + quad * 8];
        f32x4 c0 = {0.f, 0.f, 0.f, 0.f}, c1 = c0;
        c0 = __builtin_amdgcn_mfma_f32_16x16x32_bf16(aH, wsf0, c0, 0, 0, 0);
        c1 = __builtin_amdgcn_mfma_f32_16x16x32_bf16(aH, wsf1, c1, 0, 0, 0);
#pragma unroll
        for (int rr = 0; rr < 4; ++rr) {
            int t = m0 + wv * 64 + mt * 16 + quad * 4 + rr;
            if (t < 16382) {
                P[(long)b * PBSTR + (long)t * 24 + col] = f2bf(c0[rr] + sv0);
                if (col < 8)
                    P[(long)b * PBSTR + (long)t * 24 + 16 + col] = f2bf(c1[rr] + sv1);
            }
        }
    }
}

// ---------------------------------------------------------------------------
// Per-layer gated kernel v3: 128 rows/block (2 mtiles/wave), weights in
// registers, shfl_xor in-register activation. LDS ~29 KB -> 5 blocks/CU.
__global__ __launch_bounds__(256) void gated_mfma_v3(
    const u16* __restrict__ Pin,
    const u16* __restrict__ wg,   // [48][64] this layer
    const u16* __restrict__ ws,   // [32][32] this layer
    const float* __restrict__ gB, const float* __restrict__ fB,
    const float* __restrict__ sB,
    u16* __restrict__ Q, int Lout, int d, int trimOff)
{
    __shared__ __align__(16) u16 T[128 * 72];   // 18432 B
    __shared__ __align__(16) u16 H[128 * 40];   // 10240 B

    const int tid = threadIdx.x;
    const int wv = tid >> 6, lane = tid & 63, col = lane & 15, quad = lane >> 4;
    const int m0 = blockIdx.x * 128;
    const int b = blockIdx.z;
    const u16* Pb = Pin + (long)b * PBSTR;

    {
        int r = tid & 127, tap = tid >> 7;
        int t = m0 + r; if (t > Lout - 1) t = Lout - 1;
        const u16* src = Pb + (long)(t + tap * d) * 24;
        u16* dst = &T[r * 72 + tap * 32];
        *(uint4*)(dst)      = *(const uint4*)(src);
        *(uint4*)(dst + 8)  = *(const uint4*)(src + 8);
        *(uint4*)(dst + 16) = *(const uint4*)(src + 16);
        *(uint4*)(dst + 24) = (uint4){0, 0, 0, 0};
    }
    if (tid < 128) *(uint4*)&H[tid * 40 + 24] = (uint4){0, 0, 0, 0};

    short8 bgf0[3], bgf1[3];
#pragma unroll
    for (int nt = 0; nt < 3; ++nt) {
        bgf0[nt] = *(const short8*)(wg + (nt * 16 + col) * 64 + quad * 8);
        bgf1[nt] = *(const short8*)(wg + (nt * 16 + col) * 64 + 32 + quad * 8);
    }
    short8 wsf0 = *(const short8*)(ws + col * 32 + quad * 8);
    short8 wsf1 = *(const short8*)(ws + (16 + col) * 32 + quad * 8);
    const float bv0 = gB[col];
    const float bv1 = (col < 8) ? gB[16 + col] : fB[col - 8];
    const float bv2 = fB[8 + col];
    const float sv0 = sB[col];
    const float sv1 = (col < 8) ? sB[16 + col] : 0.f;

    __syncthreads();

#pragma unroll
    for (int mt = 0; mt < 2; ++mt) {
        const int r = wv * 32 + mt * 16;
        short8 a0 = *(const short8*)&T[(r + col) * 72 + quad * 8];
        short8 a1 = *(const short8*)&T[(r + col) * 72 + 32 + quad * 8];
        f32x4 ac0 = {0.f, 0.f, 0.f, 0.f}, ac1 = ac0, ac2 = ac0;
        ac0 = __builtin_amdgcn_mfma_f32_16x16x32_bf16(a0, bgf0[0], ac0, 0, 0, 0);
        ac0 = __builtin_amdgcn_mfma_f32_16x16x32_bf16(a1, bgf1[0], ac0, 0, 0, 0);
        ac1 = __builtin_amdgcn_mfma_f32_16x16x32_bf16(a0, bgf0[1], ac1, 0, 0, 0);
        ac1 = __builtin_amdgcn_mfma_f32_16x16x32_bf16(a1, bgf1[1], ac1, 0, 0, 0);
        ac2 = __builtin_amdgcn_mfma_f32_16x16x32_bf16(a0, bgf0[2], ac2, 0, 0, 0);
        ac2 = __builtin_amdgcn_mfma_f32_16x16x32_bf16(a1, bgf1[2], ac2, 0, 0, 0);

        const int lr = r + quad * 4;
#pragma unroll
        for (int rr = 0; rr < 4; ++rr) {
            float g0 = ac0[rr] + bv0;
            float m1 = ac1[rr] + bv1;
            float m2 = ac2[rr] + bv2;
            float s1 = __shfl_xor(m1, 8);
            float s2 = __shfl_xor(m2, 8);
            float f0 = (col < 8) ? s1 : s2;
            H[(lr + rr) * 40 + col] = f2bf(sigf(g0) * tanhfast(f0));
            if (col < 8)
                H[(lr + rr) * 40 + 16 + col] = f2bf(sigf(m1) * tanhfast(s2));
        }
    }
    __syncthreads();

#pragma unroll
    for (int mt = 0; mt < 2; ++mt) {
        short8 aH = *(const short8*)&H[(wv * 32 + mt * 16 + col) * 40 + quad * 8];
        f32x4 c0 = {0.f, 0.f, 0.f, 0.f}, c1 = c0;
        c0 = __builtin_amdgcn_mfma_f32_16x16x32_bf16(aH, wsf0, c0, 0, 0, 0);
        c1 = __builtin_amdgcn_mfma_f32_16x16x32_bf16(aH, wsf1, c1, 0, 0, 0);
#pragma unroll
        for (int rr = 0; rr < 4; ++rr) {
            int t = m0 + wv * 32 + mt * 16 + quad * 4 + rr;
            if (t < Lout) {
                float v0 = c0[rr] + sv0;
                if (trimOff >= 0) v0 += bf2f(Pb[(long)(t + trimOff) * 24 + col]);
                Q[(long)b * PBSTR + (long)t * 24 + col] = f2bf(v0);
                if (col < 8) {
                    float v1 = c1[rr] + sv1;
                    if (trimOff >= 0) v1 += bf2f(Pb[(long)(t + trimOff) * 24 + 16 + col]);
                    Q[(long)b * PBSTR + (long)t * 24 + 16 + col] = f2bf(v1);
                }
            }
        }
    }
}

// ---------------------------------------------------------------------------
// res-conv (K=24pad32 -> 128ch relu) + f1 (K=128 -> 256ch relu) fused.
__global__ __launch_bounds__(256) void res_f1_fused(
    const u16* __restrict__ Pfin,
    const u16* __restrict__ Wtr, const float* __restrict__ resb,
    const u16* __restrict__ Wt1, const float* __restrict__ f1b,
    u16* __restrict__ A1)
{
    __shared__ __align__(16) u16 ACCs[128 * 136];
    __shared__ __align__(16) u16 W1s[128 * 136];
    __shared__ float biasL[128];

    const int tid = threadIdx.x;
    const int wv = tid >> 6, lane = tid & 63, col = lane & 15, quad = lane >> 4;
    const int b = blockIdx.z;
    const int n0 = blockIdx.y * 128;
    const int m0 = blockIdx.x * 128;
    const u16* Pb = Pfin + (long)b * PBSTR;

    for (int i = tid; i < 2048; i += 256) {
        int rn = i >> 4, kk = i & 15;
        *(uint4*)&W1s[rn * 136 + kk * 8] = *(const uint4*)(Wt1 + (long)(n0 + rn) * 128 + kk * 8);
    }
    if (tid < 128) biasL[tid] = f1b[n0 + tid];

    short8 bfr[8];
    float rbv[8];
#pragma unroll
    for (int nt = 0; nt < 8; ++nt) {
        bfr[nt] = *(const short8*)(Wtr + (nt * 16 + col) * 32 + quad * 8);
        rbv[nt] = resb[nt * 16 + col];
    }
    short8 afr[2];
#pragma unroll
    for (int mt = 0; mt < 2; ++mt) {
        int r = m0 + wv * 32 + mt * 16 + col;
        if (r > 15359) r = 15359;
        afr[mt] = *(const short8*)(Pb + (long)r * 24 + quad * 8);
    }
    f32x4 acc[2][8];
#pragma unroll
    for (int i = 0; i < 2; ++i)
#pragma unroll
        for (int j = 0; j < 8; ++j) acc[i][j] = (f32x4){0.f, 0.f, 0.f, 0.f};
#pragma unroll
    for (int nt = 0; nt < 8; ++nt) {
        acc[0][nt] = __builtin_amdgcn_mfma_f32_16x16x32_bf16(afr[0], bfr[nt], acc[0][nt], 0, 0, 0);
        acc[1][nt] = __builtin_amdgcn_mfma_f32_16x16x32_bf16(afr[1], bfr[nt], acc[1][nt], 0, 0, 0);
    }
#pragma unroll
    for (int mt = 0; mt < 2; ++mt)
#pragma unroll
        for (int nt = 0; nt < 8; ++nt)
#pragma unroll
            for (int rr = 0; rr < 4; ++rr) {
                int lrow = wv * 32 + mt * 16 + quad * 4 + rr;
                ACCs[lrow * 136 + nt * 16 + col] = f2bf(fmaxf(acc[mt][nt][rr] + rbv[nt], 0.f));
            }
    __syncthreads();

    f32x4 acc2[2][8];
#pragma unroll
    for (int i = 0; i < 2; ++i)
#pragma unroll
        for (int j = 0; j < 8; ++j) acc2[i][j] = (f32x4){0.f, 0.f, 0.f, 0.f};
#pragma unroll
    for (int ks = 0; ks < 4; ++ks) {
        short8 am[2];
#pragma unroll
        for (int mt = 0; mt < 2; ++mt)
            am[mt] = *(const short8*)&ACCs[(wv * 32 + mt * 16 + col) * 136 + ks * 32 + quad * 8];
#pragma unroll
        for (int nt = 0; nt < 8; ++nt) {
            short8 bb = *(const short8*)&W1s[(nt * 16 + col) * 136 + ks * 32 + quad * 8];
            acc2[0][nt] = __builtin_amdgcn_mfma_f32_16x16x32_bf16(am[0], bb, acc2[0][nt], 0, 0, 0);
            acc2[1][nt] = __builtin_amdgcn_mfma_f32_16x16x32_bf16(am[1], bb, acc2[1][nt], 0, 0, 0);
        }
    }
#pragma unroll
    for (int mt = 0; mt < 2; ++mt)
#pragma unroll
        for (int nt = 0; nt < 8; ++nt)
#pragma unroll
            for (int rr = 0; rr < 4; ++rr) {
                int t = m0 + wv * 32 + mt * 16 + quad * 4 + rr;
                float v = fmaxf(acc2[mt][nt][rr] + biasL[nt * 16 + col], 0.f);
                A1[((long)b * 15360 + t) * 256 + n0 + nt * 16 + col] = f2bf(v);
            }
}

// ---------------------------------------------------------------------------
__global__ __launch_bounds__(256) void f2_softmax_v2(
    const u16* __restrict__ A, const u16* __restrict__ Wt2,
    const float* __restrict__ bias, float* __restrict__ out)
{
    __shared__ __align__(16) u16 Bs[2][256 * 40];
    __shared__ float biasL[256];
    const int tid = threadIdx.x;
    const int b = blockIdx.y;
    const int t0 = blockIdx.x * 64;
    biasL[tid] = bias[tid];

    const int wv = tid >> 6, lane = tid & 63, col = lane & 15, quad = lane >> 4;
    const u16* Ab = A + (long)b * (15360L * 256);
    const int row = t0 + wv * 16 + col;

    auto stage = [&](int kc, int buf) {
#pragma unroll
        for (int j = 0; j < 4; ++j) {
            int idx = tid * 4 + j;
            int rn = idx >> 2, kk = idx & 3;
            *(uint4*)&Bs[buf][rn * 40 + kk * 8] =
                *(const uint4*)(Wt2 + (long)rn * 256 + kc * 32 + kk * 8);
        }
    };

    short8 afr[8];
#pragma unroll
    for (int kc = 0; kc < 8; ++kc)
        afr[kc] = *(const short8*)(Ab + (long)row * 256 + kc * 32 + quad * 8);

    f32x4 acc[16];
#pragma unroll
    for (int i = 0; i < 16; ++i) acc[i] = (f32x4){0.f, 0.f, 0.f, 0.f};

    stage(0, 0);
    __syncthreads();
    for (int kc = 0; kc < 8; ++kc) {
        int buf = kc & 1;
        if (kc < 7) stage(kc + 1, buf ^ 1);
#pragma unroll
        for (int nt = 0; nt < 16; ++nt) {
            short8 bb = *(const short8*)&Bs[buf][(nt * 16 + col) * 40 + quad * 8];
            acc[nt] = __builtin_amdgcn_mfma_f32_16x16x32_bf16(afr[kc], bb, acc[nt], 0, 0, 0);
        }
        __syncthreads();
    }

#pragma unroll
    for (int r = 0; r < 4; ++r) {
        int tl = wv * 16 + quad * 4 + r;
        float v[16];
        float m = -1e30f;
#pragma unroll
        for (int nt = 0; nt < 16; ++nt) {
            v[nt] = acc[nt][r] + biasL[nt * 16 + col];
            m = fmaxf(m, v[nt]);
        }
        m = fmaxf(m, __shfl_xor(m, 1));
        m = fmaxf(m, __shfl_xor(m, 2));
        m = fmaxf(m, __shfl_xor(m, 4));
        m = fmaxf(m, __shfl_xor(m, 8));
        float s = 0.f;
#pragma unroll
        for (int nt = 0; nt < 16; ++nt) { v[nt] = __expf(v[nt] - m); s += v[nt]; }
        s += __shfl_xor(s, 1);
        s += __shfl_xor(s, 2);
        s += __shfl_xor(s, 4);
        s += __shfl_xor(s, 8);
        float inv = 1.f / s;
        float* op = out + ((long)b * 15360 + t0 + tl) * 256;
#pragma unroll
        for (int nt = 0; nt < 16; ++nt) op[nt * 16 + col] = v[nt] * inv;
    }
}

// ---------------------------------------------------------------------------
extern "C" void kernel_launch(void* const* d_in, const int* in_sizes, int n_in,
                              void* d_out, int out_size, void* d_ws, size_t ws_size,
                              hipStream_t stream)
{
    const float* x        = (const float*)d_in[0];
    const float* causal_W = (const float*)d_in[1];
    const float* causal_b = (const float*)d_in[2];
    const float* gW0      = (const float*)d_in[3];
    const float* gb0      = (const float*)d_in[4];
    const float* fW0      = (const float*)d_in[5];
    const float* fb0      = (const float*)d_in[6];
    const float* sW0      = (const float*)d_in[7];
    const float* sb0      = (const float*)d_in[8];
    const float* gate_W   = (const float*)d_in[9];
    const float* gate_b   = (const float*)d_in[10];
    const float* filter_W = (const float*)d_in[11];
    const float* filter_b = (const float*)d_in[12];
    const float* scale_W  = (const float*)d_in[13];
    const float* scale_b  = (const float*)d_in[14];
    const float* res_W    = (const float*)d_in[15];
    const float* res_b    = (const float*)d_in[16];
    const float* f1_W     = (const float*)d_in[17];
    const float* f1_b     = (const float*)d_in[18];
    const float* f2_W     = (const float*)d_in[19];
    const float* f2_b     = (const float*)d_in[20];

    char* w = (char*)d_ws;
    u16* A1   = (u16*)w;   w += (size_t)8 * 15360 * 256 * 2;
    u16* P0   = (u16*)w;   w += (size_t)8 * 16382 * 24 * 2 + 128;
    u16* P1   = (u16*)w;   w += (size_t)8 * 16382 * 24 * 2 + 128;
    u16* WtGF = (u16*)w;   w += (size_t)64 * 768 * 2;
    u16* Wt1  = (u16*)w;   w += (size_t)256 * 128 * 2;
    u16* Wt2  = (u16*)w;   w += (size_t)256 * 256 * 2;
    u16* Wtr  = (u16*)w;   w += (size_t)128 * 32 * 2;
    float* biasGF = (float*)w; w += 256;
    u16* WgfG = (u16*)w;   w += (size_t)9 * 48 * 64 * 2;
    u16* WsG  = (u16*)w;   w += (size_t)10 * 32 * 32 * 2;

    dim3 blk(256);

    build_all<<<dim3(740), blk, 0, stream>>>(
        causal_W, causal_b, gW0, gb0, fW0, fb0, WtGF, biasGF,
        f1_W, f2_W, res_W + (size_t)8 * 24 * 128,
        gate_W, filter_W, scale_W, sW0,
        Wt1, Wt2, Wtr, WgfG, WsG);

    gf_fused_v6<<<dim3(64, 1, 8), blk, 0, stream>>>(
        x, WtGF, biasGF, WsG + (size_t)9 * 1024, sb0, P0);

    u16* Pprev = P0;
    u16* Pnext = P1;
    int Lprev = 16382;
    for (int i = 0; i < 9; ++i) {
        int d = 2 << i;
        int L = Lprev - d;
        int trim = (i == 8) ? d / 2 : -1;
        gated_mfma_v3<<<dim3((L + 127) / 128, 1, 8), blk, 0, stream>>>(
            Pprev, WgfG + (size_t)i * 3072, WsG + (size_t)i * 1024,
            gate_b + i * 24, filter_b + i * 24, scale_b + i * 24,
            Pnext, L, d, trim);
        u16* tmp = Pprev; Pprev = Pnext; Pnext = tmp;
        Lprev = L;
    }

    res_f1_fused<<<dim3(120, 2, 8), blk, 0, stream>>>(
        Pprev, Wtr, res_b + 8 * 128, Wt1, f1_b, A1);

    f2_softmax_v2<<<dim3(240, 8), blk, 0, stream>>>(A1, Wt2, f2_b, (float*)d_out);
}

// Round 6
// 544.529 us; speedup vs baseline: 1.2789x; 1.0040x over previous
//
#include <hip/hip_runtime.h>
#include <math.h>

typedef unsigned short u16;
typedef __attribute__((ext_vector_type(8))) short short8;
typedef __attribute__((ext_vector_type(4))) float f32x4;

#define PBSTR ((long)16382 * 24)

__device__ __forceinline__ u16 f2bf(float f) {
    unsigned u = __float_as_uint(f);
    unsigned r = u + 0x7FFFu + ((u >> 16) & 1u);
    return (u16)(r >> 16);
}
__device__ __forceinline__ float bf2f(u16 v) { return __uint_as_float((unsigned)v << 16); }
__device__ __forceinline__ float sigf(float x) { return 1.f / (1.f + __expf(-x)); }
__device__ __forceinline__ float tanhfast(float x) { return 2.f / (1.f + __expf(-2.f * x)) - 1.f; }

// HW packed f32->bf16 (RNE, same rounding as f2bf): 1 instr per 2 values.
__device__ __forceinline__ unsigned cvtpk(float a, float b) {
    unsigned r;
    asm("v_cvt_pk_bf16_f32 %0, %1, %2" : "=v"(r) : "v"(a), "v"(b));
    return r;
}
__device__ __forceinline__ short8 ldfrag8(const float* p) {
    float4 v0 = *(const float4*)p;
    float4 v1 = *(const float4*)(p + 4);
    union { uint4 u; short8 s; } cv;
    cv.u.x = cvtpk(v0.x, v0.y); cv.u.y = cvtpk(v0.z, v0.w);
    cv.u.z = cvtpk(v1.x, v1.y); cv.u.w = cvtpk(v1.z, v1.w);
    return cv.s;
}

// async global->LDS, 16B per lane (dst = wave-uniform base + lane*16)
__device__ __forceinline__ void gload16(const float* g, float* l) {
    __builtin_amdgcn_global_load_lds(
        (const __attribute__((address_space(1))) unsigned int*)g,
        (__attribute__((address_space(3))) unsigned int*)l, 16, 0, 0);
}

// ---------------------------------------------------------------------------
// All weight-table builds in ONE launch.
__global__ __launch_bounds__(256) void build_all(
    const float* __restrict__ cW, const float* __restrict__ cb,
    const float* __restrict__ gW, const float* __restrict__ gb,
    const float* __restrict__ fW, const float* __restrict__ fb,
    u16* __restrict__ Wt, float* __restrict__ biasGF,
    const float* __restrict__ f1W, const float* __restrict__ f2W,
    const float* __restrict__ resW8,
    const float* __restrict__ gateW, const float* __restrict__ filtW,
    const float* __restrict__ sclW, const float* __restrict__ s0W,
    u16* __restrict__ Wt1, u16* __restrict__ Wt2, u16* __restrict__ Wtr,
    u16* __restrict__ Wgf, u16* __restrict__ Wsc)
{
    if (blockIdx.x < 192) {
        int idx = blockIdx.x * 256 + threadIdx.x;
        if (idx < 49152) {
            int nr = idx / 768, k = idx % 768, tau = k / 256, ci = k % 256;
            float val = 0.f;
            if (nr < 48) {
                const float* G = (nr < 24) ? gW : fW;
                int n = (nr < 24) ? nr : nr - 24;
                auto dotf = [&](int i, int j) {
                    const float* a = cW + i * 65536 + ci * 256;
                    const float* g = G + j * 6144 + n;
                    float s = 0.f;
                    for (int o = 0; o < 256; o += 4) {
                        float4 av = *(const float4*)(a + o);
                        const float* gp = g + o * 24;
                        s += av.x * gp[0] + av.y * gp[24] + av.z * gp[48] + av.w * gp[72];
                    }
                    return s;
                };
                if (tau == 0)      val = dotf(0, 0);
                else if (tau == 1) val = dotf(0, 1) + dotf(1, 0);
                else               val = dotf(1, 1);
            }
            Wt[idx] = f2bf(val);
        }
        if (blockIdx.x == 0 && threadIdx.x < 48) {
            int nr = threadIdx.x;
            const float* G = (nr < 24) ? gW : fW;
            const float* B = (nr < 24) ? gb : fb;
            int n = (nr < 24) ? nr : nr - 24;
            float s = B[n];
            for (int o = 0; o < 256; ++o) s += cb[o] * (G[o * 24 + n] + G[6144 + o * 24 + n]);
            biasGF[nr] = s;
        }
    } else {
        int idx = (blockIdx.x - 192) * 256 + threadIdx.x;
        if (idx < 32768) {
            int n = idx / 128, k = idx % 128;
            Wt1[idx] = f2bf(f1W[k * 256 + n]);
        } else if (idx < 98304) {
            int j = idx - 32768; int n = j / 256, k = j % 256;
            Wt2[j] = f2bf(f2W[k * 256 + n]);
        } else if (idx < 102400) {
            int j = idx - 98304; int n = j / 32, k = j % 32;
            Wtr[j] = (k < 24) ? f2bf(resW8[k * 128 + n]) : (u16)0;
        } else if (idx < 130048) {
            int j = idx - 102400;
            int i = j / 3072, r = (j % 3072) / 64, k = j % 64;
            float v = 0.f;
            int tap = -1, ci = 0;
            if (k < 24) { tap = 0; ci = k; }
            else if (k >= 32 && k < 56) { tap = 1; ci = k - 32; }
            if (tap >= 0) {
                const float* W = (r < 24) ? gateW : filtW;
                int co = (r < 24) ? r : r - 24;
                v = W[((i * 2 + tap) * 24 + ci) * 24 + co];
            }
            Wgf[j] = f2bf(v);
        } else if (idx < 140288) {
            int j = idx - 130048;
            int i = j / 1024, r = (j % 1024) / 32, k = j % 32;
            const float* S = (i < 9) ? (sclW + (size_t)i * 576) : s0W;
            float v = (r < 24 && k < 24) ? S[k * 24 + r] : 0.f;
            Wsc[j] = f2bf(v);
        }
    }
}

// ---------------------------------------------------------------------------
// v7: A-path via double-buffered global_load_lds (16 KB/step, async) with
// both-sides 16B-chunk XOR swizzle (chunk ^= row&7); B in LDS K-halves.
// Per-lane dependent loads eliminated -> BW-limited, not latency-limited.
__global__ __launch_bounds__(256) void gf_fused_v7(
    const float* __restrict__ x, const u16* __restrict__ Wt,
    const float* __restrict__ biasGF,
    const u16* __restrict__ ws0, const float* __restrict__ sb,
    u16* __restrict__ P)
{
    __shared__ __align__(16) union {
        u16 bs[48 * 392];   // 37632 B (one K-half of B)
        u16 H[128 * 40];    // 10240 B (epilogue)
    } U;
    __shared__ __align__(16) float ab[2][128 * 32];  // 2 x 16384 B
    // total 70400 B -> 2 blocks/CU

    const int tid = threadIdx.x;
    const int wv = tid >> 6, lane = tid & 63, col = lane & 15, quad = lane >> 4;
    const int m0 = blockIdx.x * 128;
    const int b = blockIdx.z;
    const float* xb = x + (long)b * (16384 * 256);

    // Per-thread global source offsets (floats) for the 4 staging sweeps.
    // Linear LDS chunk lin = j*256+tid holds row lin>>3, swizzled chunk
    // (lin&7): content = original chunk (lin&7)^(row&7).
    long srcoff[4];
#pragma unroll
    for (int j = 0; j < 4; ++j) {
        int lin = j * 256 + tid;
        int rl = lin >> 3;
        int r = m0 + rl;
        if (r > 16381) r = 16381;   // rows 16382/16383: content discarded
        int ii = (lin & 7) ^ (rl & 7);
        srcoff[j] = (long)r * 256 + ii * 4;
    }

    auto stageA = [&](int ks, int bufi) {
#pragma unroll
        for (int j = 0; j < 4; ++j)
            gload16(xb + srcoff[j] + ks * 32, &ab[bufi][j * 1024 + wv * 256]);
    };

    // prologue: B half 0 + A step 0
    for (int i = tid; i < 2304; i += 256) {
        int rn = i / 48, kk = i % 48;
        *(uint4*)&U.bs[rn * 392 + kk * 8] = *(const uint4*)(Wt + (long)rn * 768 + kk * 8);
    }

    short8 wsf0 = *(const short8*)(ws0 + col * 32 + quad * 8);
    short8 wsf1 = *(const short8*)(ws0 + (16 + col) * 32 + quad * 8);
    const float bv0 = biasGF[col];
    const float bv1 = (col < 8) ? biasGF[16 + col] : biasGF[24 + col - 8];
    const float bv2 = biasGF[32 + col];
    const float sv0 = sb[col];
    const float sv1 = (col < 8) ? sb[16 + col] : 0.f;

    f32x4 acc[2][3];
#pragma unroll
    for (int i = 0; i < 2; ++i)
#pragma unroll
        for (int j = 0; j < 3; ++j) acc[i][j] = (f32x4){0.f, 0.f, 0.f, 0.f};

    stageA(0, 0);
    __syncthreads();

    for (int ks = 0; ks < 24; ++ks) {
        if (ks < 23) stageA(ks + 1, (ks + 1) & 1);   // async, lands by next barrier
        if (ks == 12) {
            // B half 1 (half-0 readers done at ks=11 barrier)
            for (int i = tid; i < 2304; i += 256) {
                int rn = i / 48, kk = i % 48;
                *(uint4*)&U.bs[rn * 392 + kk * 8] =
                    *(const uint4*)(Wt + (long)rn * 768 + 384 + kk * 8);
            }
            __syncthreads();
        }
        const int cur = ks & 1;
        const int kb = (ks % 12) * 32;

        short8 a[2];
#pragma unroll
        for (int mt = 0; mt < 2; ++mt) {
            const int row = wv * 32 + mt * 16 + col;
            const int sw = row & 7;   // row base multiple of 16 -> == col&7
            const float* base = &ab[cur][row * 32];
            float4 v0 = *(const float4*)(base + ((2 * quad) ^ sw) * 4);
            float4 v1 = *(const float4*)(base + ((2 * quad + 1) ^ sw) * 4);
            union { uint4 u; short8 s8; } cv;
            cv.u.x = cvtpk(v0.x, v0.y); cv.u.y = cvtpk(v0.z, v0.w);
            cv.u.z = cvtpk(v1.x, v1.y); cv.u.w = cvtpk(v1.z, v1.w);
            a[mt] = cv.s8;
        }
#pragma unroll
        for (int nt = 0; nt < 3; ++nt) {
            short8 bb = *(const short8*)&U.bs[(nt * 16 + col) * 392 + kb + quad * 8];
            acc[0][nt] = __builtin_amdgcn_mfma_f32_16x16x32_bf16(a[0], bb, acc[0][nt], 0, 0, 0);
            acc[1][nt] = __builtin_amdgcn_mfma_f32_16x16x32_bf16(a[1], bb, acc[1][nt], 0, 0, 0);
        }
        __syncthreads();
    }

    // epilogue: in-register g/f activation (shfl_xor) -> H -> MFMA s-conv
    if (tid < 128) *(uint4*)&U.H[tid * 40 + 24] = (uint4){0, 0, 0, 0};

#pragma unroll
    for (int mt = 0; mt < 2; ++mt) {
        const int lr = wv * 32 + mt * 16 + quad * 4;
#pragma unroll
        for (int rr = 0; rr < 4; ++rr) {
            float g0 = acc[mt][0][rr] + bv0;
            float m1 = acc[mt][1][rr] + bv1;
            float m2 = acc[mt][2][rr] + bv2;
            float s1 = __shfl_xor(m1, 8);
            float s2 = __shfl_xor(m2, 8);
            float f0 = (col < 8) ? s1 : s2;
            U.H[(lr + rr) * 40 + col] = f2bf(sigf(g0) * tanhfast(f0));
            if (col < 8)
                U.H[(lr + rr) * 40 + 16 + col] = f2bf(sigf(m1) * tanhfast(s2));
        }
    }
    __syncthreads();

#pragma unroll
    for (int mt = 0; mt < 2; ++mt) {
        short8 aH = *(const short8*)&U.H[(wv * 32 + mt * 16 + col) * 40 + quad * 8];
        f32x4 c0 = {0.f, 0.f, 0.f, 0.f}, c1 = c0;
        c0 = __builtin_amdgcn_mfma_f32_16x16x32_bf16(aH, wsf0, c0, 0, 0, 0);
        c1 = __builtin_amdgcn_mfma_f32_16x16x32_bf16(aH, wsf1, c1, 0, 0, 0);
#pragma unroll
        for (int rr = 0; rr < 4; ++rr) {
            int t = m0 + wv * 32 + mt * 16 + quad * 4 + rr;
            if (t < 16382) {
                P[(long)b * PBSTR + (long)t * 24 + col] = f2bf(c0[rr] + sv0);
                if (col < 8)
                    P[(long)b * PBSTR + (long)t * 24 + 16 + col] = f2bf(c1[rr] + sv1);
            }
        }
    }
}

// ---------------------------------------------------------------------------
// Per-layer gated kernel v3 (unchanged from R5).
__global__ __launch_bounds__(256) void gated_mfma_v3(
    const u16* __restrict__ Pin,
    const u16* __restrict__ wg,
    const u16* __restrict__ ws,
    const float* __restrict__ gB, const float* __restrict__ fB,
    const float* __restrict__ sB,
    u16* __restrict__ Q, int Lout, int d, int trimOff)
{
    __shared__ __align__(16) u16 T[128 * 72];
    __shared__ __align__(16) u16 H[128 * 40];

    const int tid = threadIdx.x;
    const int wv = tid >> 6, lane = tid & 63, col = lane & 15, quad = lane >> 4;
    const int m0 = blockIdx.x * 128;
    const int b = blockIdx.z;
    const u16* Pb = Pin + (long)b * PBSTR;

    {
        int r = tid & 127, tap = tid >> 7;
        int t = m0 + r; if (t > Lout - 1) t = Lout - 1;
        const u16* src = Pb + (long)(t + tap * d) * 24;
        u16* dst = &T[r * 72 + tap * 32];
        *(uint4*)(dst)      = *(const uint4*)(src);
        *(uint4*)(dst + 8)  = *(const uint4*)(src + 8);
        *(uint4*)(dst + 16) = *(const uint4*)(src + 16);
        *(uint4*)(dst + 24) = (uint4){0, 0, 0, 0};
    }
    if (tid < 128) *(uint4*)&H[tid * 40 + 24] = (uint4){0, 0, 0, 0};

    short8 bgf0[3], bgf1[3];
#pragma unroll
    for (int nt = 0; nt < 3; ++nt) {
        bgf0[nt] = *(const short8*)(wg + (nt * 16 + col) * 64 + quad * 8);
        bgf1[nt] = *(const short8*)(wg + (nt * 16 + col) * 64 + 32 + quad * 8);
    }
    short8 wsf0 = *(const short8*)(ws + col * 32 + quad * 8);
    short8 wsf1 = *(const short8*)(ws + (16 + col) * 32 + quad * 8);
    const float bv0 = gB[col];
    const float bv1 = (col < 8) ? gB[16 + col] : fB[col - 8];
    const float bv2 = fB[8 + col];
    const float sv0 = sB[col];
    const float sv1 = (col < 8) ? sB[16 + col] : 0.f;

    __syncthreads();

#pragma unroll
    for (int mt = 0; mt < 2; ++mt) {
        const int r = wv * 32 + mt * 16;
        short8 a0 = *(const short8*)&T[(r + col) * 72 + quad * 8];
        short8 a1 = *(const short8*)&T[(r + col) * 72 + 32 + quad * 8];
        f32x4 ac0 = {0.f, 0.f, 0.f, 0.f}, ac1 = ac0, ac2 = ac0;
        ac0 = __builtin_amdgcn_mfma_f32_16x16x32_bf16(a0, bgf0[0], ac0, 0, 0, 0);
        ac0 = __builtin_amdgcn_mfma_f32_16x16x32_bf16(a1, bgf1[0], ac0, 0, 0, 0);
        ac1 = __builtin_amdgcn_mfma_f32_16x16x32_bf16(a0, bgf0[1], ac1, 0, 0, 0);
        ac1 = __builtin_amdgcn_mfma_f32_16x16x32_bf16(a1, bgf1[1], ac1, 0, 0, 0);
        ac2 = __builtin_amdgcn_mfma_f32_16x16x32_bf16(a0, bgf0[2], ac2, 0, 0, 0);
        ac2 = __builtin_amdgcn_mfma_f32_16x16x32_bf16(a1, bgf1[2], ac2, 0, 0, 0);

        const int lr = r + quad * 4;
#pragma unroll
        for (int rr = 0; rr < 4; ++rr) {
            float g0 = ac0[rr] + bv0;
            float m1 = ac1[rr] + bv1;
            float m2 = ac2[rr] + bv2;
            float s1 = __shfl_xor(m1, 8);
            float s2 = __shfl_xor(m2, 8);
            float f0 = (col < 8) ? s1 : s2;
            H[(lr + rr) * 40 + col] = f2bf(sigf(g0) * tanhfast(f0));
            if (col < 8)
                H[(lr + rr) * 40 + 16 + col] = f2bf(sigf(m1) * tanhfast(s2));
        }
    }
    __syncthreads();

#pragma unroll
    for (int mt = 0; mt < 2; ++mt) {
        short8 aH = *(const short8*)&H[(wv * 32 + mt * 16 + col) * 40 + quad * 8];
        f32x4 c0 = {0.f, 0.f, 0.f, 0.f}, c1 = c0;
        c0 = __builtin_amdgcn_mfma_f32_16x16x32_bf16(aH, wsf0, c0, 0, 0, 0);
        c1 = __builtin_amdgcn_mfma_f32_16x16x32_bf16(aH, wsf1, c1, 0, 0, 0);
#pragma unroll
        for (int rr = 0; rr < 4; ++rr) {
            int t = m0 + wv * 32 + mt * 16 + quad * 4 + rr;
            if (t < Lout) {
                float v0 = c0[rr] + sv0;
                if (trimOff >= 0) v0 += bf2f(Pb[(long)(t + trimOff) * 24 + col]);
                Q[(long)b * PBSTR + (long)t * 24 + col] = f2bf(v0);
                if (col < 8) {
                    float v1 = c1[rr] + sv1;
                    if (trimOff >= 0) v1 += bf2f(Pb[(long)(t + trimOff) * 24 + 16 + col]);
                    Q[(long)b * PBSTR + (long)t * 24 + 16 + col] = f2bf(v1);
                }
            }
        }
    }
}

// ---------------------------------------------------------------------------
// res-conv + f1 fused (unchanged from R5).
__global__ __launch_bounds__(256) void res_f1_fused(
    const u16* __restrict__ Pfin,
    const u16* __restrict__ Wtr, const float* __restrict__ resb,
    const u16* __restrict__ Wt1, const float* __restrict__ f1b,
    u16* __restrict__ A1)
{
    __shared__ __align__(16) u16 ACCs[128 * 136];
    __shared__ __align__(16) u16 W1s[128 * 136];
    __shared__ float biasL[128];

    const int tid = threadIdx.x;
    const int wv = tid >> 6, lane = tid & 63, col = lane & 15, quad = lane >> 4;
    const int b = blockIdx.z;
    const int n0 = blockIdx.y * 128;
    const int m0 = blockIdx.x * 128;
    const u16* Pb = Pfin + (long)b * PBSTR;

    for (int i = tid; i < 2048; i += 256) {
        int rn = i >> 4, kk = i & 15;
        *(uint4*)&W1s[rn * 136 + kk * 8] = *(const uint4*)(Wt1 + (long)(n0 + rn) * 128 + kk * 8);
    }
    if (tid < 128) biasL[tid] = f1b[n0 + tid];

    short8 bfr[8];
    float rbv[8];
#pragma unroll
    for (int nt = 0; nt < 8; ++nt) {
        bfr[nt] = *(const short8*)(Wtr + (nt * 16 + col) * 32 + quad * 8);
        rbv[nt] = resb[nt * 16 + col];
    }
    short8 afr[2];
#pragma unroll
    for (int mt = 0; mt < 2; ++mt) {
        int r = m0 + wv * 32 + mt * 16 + col;
        if (r > 15359) r = 15359;
        afr[mt] = *(const short8*)(Pb + (long)r * 24 + quad * 8);
    }
    f32x4 acc[2][8];
#pragma unroll
    for (int i = 0; i < 2; ++i)
#pragma unroll
        for (int j = 0; j < 8; ++j) acc[i][j] = (f32x4){0.f, 0.f, 0.f, 0.f};
#pragma unroll
    for (int nt = 0; nt < 8; ++nt) {
        acc[0][nt] = __builtin_amdgcn_mfma_f32_16x16x32_bf16(afr[0], bfr[nt], acc[0][nt], 0, 0, 0);
        acc[1][nt] = __builtin_amdgcn_mfma_f32_16x16x32_bf16(afr[1], bfr[nt], acc[1][nt], 0, 0, 0);
    }
#pragma unroll
    for (int mt = 0; mt < 2; ++mt)
#pragma unroll
        for (int nt = 0; nt < 8; ++nt)
#pragma unroll
            for (int rr = 0; rr < 4; ++rr) {
                int lrow = wv * 32 + mt * 16 + quad * 4 + rr;
                ACCs[lrow * 136 + nt * 16 + col] = f2bf(fmaxf(acc[mt][nt][rr] + rbv[nt], 0.f));
            }
    __syncthreads();

    f32x4 acc2[2][8];
#pragma unroll
    for (int i = 0; i < 2; ++i)
#pragma unroll
        for (int j = 0; j < 8; ++j) acc2[i][j] = (f32x4){0.f, 0.f, 0.f, 0.f};
#pragma unroll
    for (int ks = 0; ks < 4; ++ks) {
        short8 am[2];
#pragma unroll
        for (int mt = 0; mt < 2; ++mt)
            am[mt] = *(const short8*)&ACCs[(wv * 32 + mt * 16 + col) * 136 + ks * 32 + quad * 8];
#pragma unroll
        for (int nt = 0; nt < 8; ++nt) {
            short8 bb = *(const short8*)&W1s[(nt * 16 + col) * 136 + ks * 32 + quad * 8];
            acc2[0][nt] = __builtin_amdgcn_mfma_f32_16x16x32_bf16(am[0], bb, acc2[0][nt], 0, 0, 0);
            acc2[1][nt] = __builtin_amdgcn_mfma_f32_16x16x32_bf16(am[1], bb, acc2[1][nt], 0, 0, 0);
        }
    }
#pragma unroll
    for (int mt = 0; mt < 2; ++mt)
#pragma unroll
        for (int nt = 0; nt < 8; ++nt)
#pragma unroll
            for (int rr = 0; rr < 4; ++rr) {
                int t = m0 + wv * 32 + mt * 16 + quad * 4 + rr;
                float v = fmaxf(acc2[mt][nt][rr] + biasL[nt * 16 + col], 0.f);
                A1[((long)b * 15360 + t) * 256 + n0 + nt * 16 + col] = f2bf(v);
            }
}

// ---------------------------------------------------------------------------
__global__ __launch_bounds__(256) void f2_softmax_v2(
    const u16* __restrict__ A, const u16* __restrict__ Wt2,
    const float* __restrict__ bias, float* __restrict__ out)
{
    __shared__ __align__(16) u16 Bs[2][256 * 40];
    __shared__ float biasL[256];
    const int tid = threadIdx.x;
    const int b = blockIdx.y;
    const int t0 = blockIdx.x * 64;
    biasL[tid] = bias[tid];

    const int wv = tid >> 6, lane = tid & 63, col = lane & 15, quad = lane >> 4;
    const u16* Ab = A + (long)b * (15360L * 256);
    const int row = t0 + wv * 16 + col;

    auto stage = [&](int kc, int buf) {
#pragma unroll
        for (int j = 0; j < 4; ++j) {
            int idx = tid * 4 + j;
            int rn = idx >> 2, kk = idx & 3;
            *(uint4*)&Bs[buf][rn * 40 + kk * 8] =
                *(const uint4*)(Wt2 + (long)rn * 256 + kc * 32 + kk * 8);
        }
    };

    short8 afr[8];
#pragma unroll
    for (int kc = 0; kc < 8; ++kc)
        afr[kc] = *(const short8*)(Ab + (long)row * 256 + kc * 32 + quad * 8);

    f32x4 acc[16];
#pragma unroll
    for (int i = 0; i < 16; ++i) acc[i] = (f32x4){0.f, 0.f, 0.f, 0.f};

    stage(0, 0);
    __syncthreads();
    for (int kc = 0; kc < 8; ++kc) {
        int buf = kc & 1;
        if (kc < 7) stage(kc + 1, buf ^ 1);
#pragma unroll
        for (int nt = 0; nt < 16; ++nt) {
            short8 bb = *(const short8*)&Bs[buf][(nt * 16 + col) * 40 + quad * 8];
            acc[nt] = __builtin_amdgcn_mfma_f32_16x16x32_bf16(afr[kc], bb, acc[nt], 0, 0, 0);
        }
        __syncthreads();
    }

#pragma unroll
    for (int r = 0; r < 4; ++r) {
        int tl = wv * 16 + quad * 4 + r;
        float v[16];
        float m = -1e30f;
#pragma unroll
        for (int nt = 0; nt < 16; ++nt) {
            v[nt] = acc[nt][r] + biasL[nt * 16 + col];
            m = fmaxf(m, v[nt]);
        }
        m = fmaxf(m, __shfl_xor(m, 1));
        m = fmaxf(m, __shfl_xor(m, 2));
        m = fmaxf(m, __shfl_xor(m, 4));
        m = fmaxf(m, __shfl_xor(m, 8));
        float s = 0.f;
#pragma unroll
        for (int nt = 0; nt < 16; ++nt) { v[nt] = __expf(v[nt] - m); s += v[nt]; }
        s += __shfl_xor(s, 1);
        s += __shfl_xor(s, 2);
        s += __shfl_xor(s, 4);
        s += __shfl_xor(s, 8);
        float inv = 1.f / s;
        float* op = out + ((long)b * 15360 + t0 + tl) * 256;
#pragma unroll
        for (int nt = 0; nt < 16; ++nt) op[nt * 16 + col] = v[nt] * inv;
    }
}

// ---------------------------------------------------------------------------
extern "C" void kernel_launch(void* const* d_in, const int* in_sizes, int n_in,
                              void* d_out, int out_size, void* d_ws, size_t ws_size,
                              hipStream_t stream)
{
    const float* x        = (const float*)d_in[0];
    const float* causal_W = (const float*)d_in[1];
    const float* causal_b = (const float*)d_in[2];
    const float* gW0      = (const float*)d_in[3];
    const float* gb0      = (const float*)d_in[4];
    const float* fW0      = (const float*)d_in[5];
    const float* fb0      = (const float*)d_in[6];
    const float* sW0      = (const float*)d_in[7];
    const float* sb0      = (const float*)d_in[8];
    const float* gate_W   = (const float*)d_in[9];
    const float* gate_b   = (const float*)d_in[10];
    const float* filter_W = (const float*)d_in[11];
    const float* filter_b = (const float*)d_in[12];
    const float* scale_W  = (const float*)d_in[13];
    const float* scale_b  = (const float*)d_in[14];
    const float* res_W    = (const float*)d_in[15];
    const float* res_b    = (const float*)d_in[16];
    const float* f1_W     = (const float*)d_in[17];
    const float* f1_b     = (const float*)d_in[18];
    const float* f2_W     = (const float*)d_in[19];
    const float* f2_b     = (const float*)d_in[20];

    char* w = (char*)d_ws;
    u16* A1   = (u16*)w;   w += (size_t)8 * 15360 * 256 * 2;
    u16* P0   = (u16*)w;   w += (size_t)8 * 16382 * 24 * 2 + 128;
    u16* P1   = (u16*)w;   w += (size_t)8 * 16382 * 24 * 2 + 128;
    u16* WtGF = (u16*)w;   w += (size_t)64 * 768 * 2;
    u16* Wt1  = (u16*)w;   w += (size_t)256 * 128 * 2;
    u16* Wt2  = (u16*)w;   w += (size_t)256 * 256 * 2;
    u16* Wtr  = (u16*)w;   w += (size_t)128 * 32 * 2;
    float* biasGF = (float*)w; w += 256;
    u16* WgfG = (u16*)w;   w += (size_t)9 * 48 * 64 * 2;
    u16* WsG  = (u16*)w;   w += (size_t)10 * 32 * 32 * 2;

    dim3 blk(256);

    build_all<<<dim3(740), blk, 0, stream>>>(
        causal_W, causal_b, gW0, gb0, fW0, fb0, WtGF, biasGF,
        f1_W, f2_W, res_W + (size_t)8 * 24 * 128,
        gate_W, filter_W, scale_W, sW0,
        Wt1, Wt2, Wtr, WgfG, WsG);

    gf_fused_v7<<<dim3(128, 1, 8), blk, 0, stream>>>(
        x, WtGF, biasGF, WsG + (size_t)9 * 1024, sb0, P0);

    u16* Pprev = P0;
    u16* Pnext = P1;
    int Lprev = 16382;
    for (int i = 0; i < 9; ++i) {
        int d = 2 << i;
        int L = Lprev - d;
        int trim = (i == 8) ? d / 2 : -1;
        gated_mfma_v3<<<dim3((L + 127) / 128, 1, 8), blk, 0, stream>>>(
            Pprev, WgfG + (size_t)i * 3072, WsG + (size_t)i * 1024,
            gate_b + i * 24, filter_b + i * 24, scale_b + i * 24,
            Pnext, L, d, trim);
        u16* tmp = Pprev; Pprev = Pnext; Pnext = tmp;
        Lprev = L;
    }

    res_f1_fused<<<dim3(120, 2, 8), blk, 0, stream>>>(
        Pprev, Wtr, res_b + 8 * 128, Wt1, f1_b, A1);

    f2_softmax_v2<<<dim3(240, 8), blk, 0, stream>>>(A1, Wt2, f2_b, (float*)d_out);
}

// Round 7
// 515.099 us; speedup vs baseline: 1.3519x; 1.0571x over previous
//
#include <hip/hip_runtime.h>
#include <math.h>

typedef unsigned short u16;
typedef __attribute__((ext_vector_type(8))) short short8;
typedef __attribute__((ext_vector_type(4))) float f32x4;

#define PBSTR ((long)16382 * 24)

__device__ __forceinline__ u16 f2bf(float f) {
    unsigned u = __float_as_uint(f);
    unsigned r = u + 0x7FFFu + ((u >> 16) & 1u);
    return (u16)(r >> 16);
}
__device__ __forceinline__ float bf2f(u16 v) { return __uint_as_float((unsigned)v << 16); }
__device__ __forceinline__ float sigf(float x) { return 1.f / (1.f + __expf(-x)); }
__device__ __forceinline__ float tanhfast(float x) { return 2.f / (1.f + __expf(-2.f * x)) - 1.f; }

// HW packed f32->bf16 (RNE, same rounding as f2bf): 1 instr per 2 values.
__device__ __forceinline__ unsigned cvtpk(float a, float b) {
    unsigned r;
    asm("v_cvt_pk_bf16_f32 %0, %1, %2" : "=v"(r) : "v"(a), "v"(b));
    return r;
}

// ---------------------------------------------------------------------------
// All weight-table builds in ONE launch.
__global__ __launch_bounds__(256) void build_all(
    const float* __restrict__ cW, const float* __restrict__ cb,
    const float* __restrict__ gW, const float* __restrict__ gb,
    const float* __restrict__ fW, const float* __restrict__ fb,
    u16* __restrict__ Wt, float* __restrict__ biasGF,
    const float* __restrict__ f1W, const float* __restrict__ f2W,
    const float* __restrict__ resW8,
    const float* __restrict__ gateW, const float* __restrict__ filtW,
    const float* __restrict__ sclW, const float* __restrict__ s0W,
    u16* __restrict__ Wt1, u16* __restrict__ Wt2, u16* __restrict__ Wtr,
    u16* __restrict__ Wgf, u16* __restrict__ Wsc)
{
    if (blockIdx.x < 192) {
        int idx = blockIdx.x * 256 + threadIdx.x;
        if (idx < 49152) {
            int nr = idx / 768, k = idx % 768, tau = k / 256, ci = k % 256;
            float val = 0.f;
            if (nr < 48) {
                const float* G = (nr < 24) ? gW : fW;
                int n = (nr < 24) ? nr : nr - 24;
                auto dotf = [&](int i, int j) {
                    const float* a = cW + i * 65536 + ci * 256;
                    const float* g = G + j * 6144 + n;
                    float s = 0.f;
                    for (int o = 0; o < 256; o += 4) {
                        float4 av = *(const float4*)(a + o);
                        const float* gp = g + o * 24;
                        s += av.x * gp[0] + av.y * gp[24] + av.z * gp[48] + av.w * gp[72];
                    }
                    return s;
                };
                if (tau == 0)      val = dotf(0, 0);
                else if (tau == 1) val = dotf(0, 1) + dotf(1, 0);
                else               val = dotf(1, 1);
            }
            Wt[idx] = f2bf(val);
        }
        if (blockIdx.x == 0 && threadIdx.x < 48) {
            int nr = threadIdx.x;
            const float* G = (nr < 24) ? gW : fW;
            const float* B = (nr < 24) ? gb : fb;
            int n = (nr < 24) ? nr : nr - 24;
            float s = B[n];
            for (int o = 0; o < 256; ++o) s += cb[o] * (G[o * 24 + n] + G[6144 + o * 24 + n]);
            biasGF[nr] = s;
        }
    } else {
        int idx = (blockIdx.x - 192) * 256 + threadIdx.x;
        if (idx < 32768) {
            int n = idx / 128, k = idx % 128;
            Wt1[idx] = f2bf(f1W[k * 256 + n]);
        } else if (idx < 98304) {
            int j = idx - 32768; int n = j / 256, k = j % 256;
            Wt2[j] = f2bf(f2W[k * 256 + n]);
        } else if (idx < 102400) {
            int j = idx - 98304; int n = j / 32, k = j % 32;
            Wtr[j] = (k < 24) ? f2bf(resW8[k * 128 + n]) : (u16)0;
        } else if (idx < 130048) {
            int j = idx - 102400;
            int i = j / 3072, r = (j % 3072) / 64, k = j % 64;
            float v = 0.f;
            int tap = -1, ci = 0;
            if (k < 24) { tap = 0; ci = k; }
            else if (k >= 32 && k < 56) { tap = 1; ci = k - 32; }
            if (tap >= 0) {
                const float* W = (r < 24) ? gateW : filtW;
                int co = (r < 24) ? r : r - 24;
                v = W[((i * 2 + tap) * 24 + ci) * 24 + co];
            }
            Wgf[j] = f2bf(v);
        } else if (idx < 140288) {
            int j = idx - 130048;
            int i = j / 1024, r = (j % 1024) / 32, k = j % 32;
            const float* S = (i < 9) ? (sclW + (size_t)i * 576) : s0W;
            float v = (r < 24 && k < 24) ? S[k * 24 + r] : 0.f;
            Wsc[j] = f2bf(v);
        }
    }
}

// ---------------------------------------------------------------------------
// v8: whole-tile contiguous staging. 64-row block; A-tile read end-to-end
// (16 sweeps x 4KB/wave contiguous), cvt_pk->bf16, XOR-swizzled LDS tile
// (chunk ^= row&7, both sides). Inner loop: LDS-only, barrier-free.
// All prior variants read 128B-per-1KB strided -> stuck at ~2 TB/s DRAM.
__global__ __launch_bounds__(256) void gf_fused_v8(
    const float* __restrict__ x, const u16* __restrict__ Wt,
    const float* __restrict__ biasGF,
    const u16* __restrict__ ws0, const float* __restrict__ sb,
    u16* __restrict__ P)
{
    __shared__ __align__(16) union {
        u16 bs[48 * 392];   // 37632 B (one K-half of B)
        u16 H[64 * 40];     // epilogue scratch
    } U;
    __shared__ __align__(16) u16 A[64 * 256];   // 32768 B bf16 A-tile
    // total 70400 B -> 2 blocks/CU

    const int tid = threadIdx.x;
    const int wv = tid >> 6, lane = tid & 63, col = lane & 15, quad = lane >> 4;
    const int m0 = blockIdx.x * 64;
    const int b = blockIdx.z;
    const float* xb = x + (long)b * (16384 * 256);

    // stage B half 0
    for (int i = tid; i < 2304; i += 256) {
        int rn = i / 48, kk = i % 48;
        *(uint4*)&U.bs[rn * 392 + kk * 8] = *(const uint4*)(Wt + (long)rn * 768 + kk * 8);
    }

    // stage A: contiguous sweeps. lin = j*256+tid: row rl = lin>>6 (64 rows),
    // 16B fp32 chunk c = lin&63. Wave reads 4KB sequential per sweep.
    // bf16 8B slot stored at c ^ ((rl&7)<<1)  (== 16B-chunk XOR rl&7).
#pragma unroll
    for (int j = 0; j < 16; ++j) {
        int lin = j * 256 + tid;
        int rl = lin >> 6, c = lin & 63;
        int r = m0 + rl; if (r > 16381) r = 16381;
        float4 v = *(const float4*)(xb + (long)r * 256 + c * 4);
        uint2 w2;
        w2.x = cvtpk(v.x, v.y); w2.y = cvtpk(v.z, v.w);
        *(uint2*)&A[rl * 256 + (c ^ ((rl & 7) << 1)) * 4] = w2;
    }

    short8 wsf0 = *(const short8*)(ws0 + col * 32 + quad * 8);
    short8 wsf1 = *(const short8*)(ws0 + (16 + col) * 32 + quad * 8);
    const float bv0 = biasGF[col];
    const float bv1 = (col < 8) ? biasGF[16 + col] : biasGF[24 + col - 8];
    const float bv2 = biasGF[32 + col];
    const float sv0 = sb[col];
    const float sv1 = (col < 8) ? sb[16 + col] : 0.f;

    f32x4 acc[3];
#pragma unroll
    for (int j = 0; j < 3; ++j) acc[j] = (f32x4){0.f, 0.f, 0.f, 0.f};

    const int arow = wv * 16 + col;          // this lane's A row
    const int asw = arow & 7;                // swizzle key
    __syncthreads();

#pragma unroll
    for (int half = 0; half < 2; ++half) {
        if (half) {
            __syncthreads();
            for (int i = tid; i < 2304; i += 256) {
                int rn = i / 48, kk = i % 48;
                *(uint4*)&U.bs[rn * 392 + kk * 8] =
                    *(const uint4*)(Wt + (long)rn * 768 + 384 + kk * 8);
            }
            __syncthreads();
        }
#pragma unroll
        for (int s = 0; s < 12; ++s) {
            const int ks = half * 12 + s;
            short8 a = *(const short8*)&A[arow * 256 + (((ks * 4 + quad) ^ asw) << 3)];
#pragma unroll
            for (int nt = 0; nt < 3; ++nt) {
                short8 bb = *(const short8*)&U.bs[(nt * 16 + col) * 392 + s * 32 + quad * 8];
                acc[nt] = __builtin_amdgcn_mfma_f32_16x16x32_bf16(a, bb, acc[nt], 0, 0, 0);
            }
        }
    }

    __syncthreads();   // bs dead; reuse as H
    if (tid < 64) *(uint4*)&U.H[tid * 40 + 24] = (uint4){0, 0, 0, 0};

    {
        const int lr = wv * 16 + quad * 4;
#pragma unroll
        for (int rr = 0; rr < 4; ++rr) {
            float g0 = acc[0][rr] + bv0;
            float m1 = acc[1][rr] + bv1;
            float m2 = acc[2][rr] + bv2;
            float s1 = __shfl_xor(m1, 8);
            float s2 = __shfl_xor(m2, 8);
            float f0 = (col < 8) ? s1 : s2;
            U.H[(lr + rr) * 40 + col] = f2bf(sigf(g0) * tanhfast(f0));
            if (col < 8)
                U.H[(lr + rr) * 40 + 16 + col] = f2bf(sigf(m1) * tanhfast(s2));
        }
    }
    __syncthreads();

    {
        short8 aH = *(const short8*)&U.H[(wv * 16 + col) * 40 + quad * 8];
        f32x4 c0 = {0.f, 0.f, 0.f, 0.f}, c1 = c0;
        c0 = __builtin_amdgcn_mfma_f32_16x16x32_bf16(aH, wsf0, c0, 0, 0, 0);
        c1 = __builtin_amdgcn_mfma_f32_16x16x32_bf16(aH, wsf1, c1, 0, 0, 0);
#pragma unroll
        for (int rr = 0; rr < 4; ++rr) {
            int t = m0 + wv * 16 + quad * 4 + rr;
            if (t < 16382) {
                P[(long)b * PBSTR + (long)t * 24 + col] = f2bf(c0[rr] + sv0);
                if (col < 8)
                    P[(long)b * PBSTR + (long)t * 24 + 16 + col] = f2bf(c1[rr] + sv1);
            }
        }
    }
}

// ---------------------------------------------------------------------------
// Per-layer gated kernel v3 (unchanged).
__global__ __launch_bounds__(256) void gated_mfma_v3(
    const u16* __restrict__ Pin,
    const u16* __restrict__ wg,
    const u16* __restrict__ ws,
    const float* __restrict__ gB, const float* __restrict__ fB,
    const float* __restrict__ sB,
    u16* __restrict__ Q, int Lout, int d, int trimOff)
{
    __shared__ __align__(16) u16 T[128 * 72];
    __shared__ __align__(16) u16 H[128 * 40];

    const int tid = threadIdx.x;
    const int wv = tid >> 6, lane = tid & 63, col = lane & 15, quad = lane >> 4;
    const int m0 = blockIdx.x * 128;
    const int b = blockIdx.z;
    const u16* Pb = Pin + (long)b * PBSTR;

    {
        int r = tid & 127, tap = tid >> 7;
        int t = m0 + r; if (t > Lout - 1) t = Lout - 1;
        const u16* src = Pb + (long)(t + tap * d) * 24;
        u16* dst = &T[r * 72 + tap * 32];
        *(uint4*)(dst)      = *(const uint4*)(src);
        *(uint4*)(dst + 8)  = *(const uint4*)(src + 8);
        *(uint4*)(dst + 16) = *(const uint4*)(src + 16);
        *(uint4*)(dst + 24) = (uint4){0, 0, 0, 0};
    }
    if (tid < 128) *(uint4*)&H[tid * 40 + 24] = (uint4){0, 0, 0, 0};

    short8 bgf0[3], bgf1[3];
#pragma unroll
    for (int nt = 0; nt < 3; ++nt) {
        bgf0[nt] = *(const short8*)(wg + (nt * 16 + col) * 64 + quad * 8);
        bgf1[nt] = *(const short8*)(wg + (nt * 16 + col) * 64 + 32 + quad * 8);
    }
    short8 wsf0 = *(const short8*)(ws + col * 32 + quad * 8);
    short8 wsf1 = *(const short8*)(ws + (16 + col) * 32 + quad * 8);
    const float bv0 = gB[col];
    const float bv1 = (col < 8) ? gB[16 + col] : fB[col - 8];
    const float bv2 = fB[8 + col];
    const float sv0 = sB[col];
    const float sv1 = (col < 8) ? sB[16 + col] : 0.f;

    __syncthreads();

#pragma unroll
    for (int mt = 0; mt < 2; ++mt) {
        const int r = wv * 32 + mt * 16;
        short8 a0 = *(const short8*)&T[(r + col) * 72 + quad * 8];
        short8 a1 = *(const short8*)&T[(r + col) * 72 + 32 + quad * 8];
        f32x4 ac0 = {0.f, 0.f, 0.f, 0.f}, ac1 = ac0, ac2 = ac0;
        ac0 = __builtin_amdgcn_mfma_f32_16x16x32_bf16(a0, bgf0[0], ac0, 0, 0, 0);
        ac0 = __builtin_amdgcn_mfma_f32_16x16x32_bf16(a1, bgf1[0], ac0, 0, 0, 0);
        ac1 = __builtin_amdgcn_mfma_f32_16x16x32_bf16(a0, bgf0[1], ac1, 0, 0, 0);
        ac1 = __builtin_amdgcn_mfma_f32_16x16x32_bf16(a1, bgf1[1], ac1, 0, 0, 0);
        ac2 = __builtin_amdgcn_mfma_f32_16x16x32_bf16(a0, bgf0[2], ac2, 0, 0, 0);
        ac2 = __builtin_amdgcn_mfma_f32_16x16x32_bf16(a1, bgf1[2], ac2, 0, 0, 0);

        const int lr = r + quad * 4;
#pragma unroll
        for (int rr = 0; rr < 4; ++rr) {
            float g0 = ac0[rr] + bv0;
            float m1 = ac1[rr] + bv1;
            float m2 = ac2[rr] + bv2;
            float s1 = __shfl_xor(m1, 8);
            float s2 = __shfl_xor(m2, 8);
            float f0 = (col < 8) ? s1 : s2;
            H[(lr + rr) * 40 + col] = f2bf(sigf(g0) * tanhfast(f0));
            if (col < 8)
                H[(lr + rr) * 40 + 16 + col] = f2bf(sigf(m1) * tanhfast(s2));
        }
    }
    __syncthreads();

#pragma unroll
    for (int mt = 0; mt < 2; ++mt) {
        short8 aH = *(const short8*)&H[(wv * 32 + mt * 16 + col) * 40 + quad * 8];
        f32x4 c0 = {0.f, 0.f, 0.f, 0.f}, c1 = c0;
        c0 = __builtin_amdgcn_mfma_f32_16x16x32_bf16(aH, wsf0, c0, 0, 0, 0);
        c1 = __builtin_amdgcn_mfma_f32_16x16x32_bf16(aH, wsf1, c1, 0, 0, 0);
#pragma unroll
        for (int rr = 0; rr < 4; ++rr) {
            int t = m0 + wv * 32 + mt * 16 + quad * 4 + rr;
            if (t < Lout) {
                float v0 = c0[rr] + sv0;
                if (trimOff >= 0) v0 += bf2f(Pb[(long)(t + trimOff) * 24 + col]);
                Q[(long)b * PBSTR + (long)t * 24 + col] = f2bf(v0);
                if (col < 8) {
                    float v1 = c1[rr] + sv1;
                    if (trimOff >= 0) v1 += bf2f(Pb[(long)(t + trimOff) * 24 + 16 + col]);
                    Q[(long)b * PBSTR + (long)t * 24 + 16 + col] = f2bf(v1);
                }
            }
        }
    }
}

// ---------------------------------------------------------------------------
// res-conv + f1 fused (unchanged).
__global__ __launch_bounds__(256) void res_f1_fused(
    const u16* __restrict__ Pfin,
    const u16* __restrict__ Wtr, const float* __restrict__ resb,
    const u16* __restrict__ Wt1, const float* __restrict__ f1b,
    u16* __restrict__ A1)
{
    __shared__ __align__(16) u16 ACCs[128 * 136];
    __shared__ __align__(16) u16 W1s[128 * 136];
    __shared__ float biasL[128];

    const int tid = threadIdx.x;
    const int wv = tid >> 6, lane = tid & 63, col = lane & 15, quad = lane >> 4;
    const int b = blockIdx.z;
    const int n0 = blockIdx.y * 128;
    const int m0 = blockIdx.x * 128;
    const u16* Pb = Pfin + (long)b * PBSTR;

    for (int i = tid; i < 2048; i += 256) {
        int rn = i >> 4, kk = i & 15;
        *(uint4*)&W1s[rn * 136 + kk * 8] = *(const uint4*)(Wt1 + (long)(n0 + rn) * 128 + kk * 8);
    }
    if (tid < 128) biasL[tid] = f1b[n0 + tid];

    short8 bfr[8];
    float rbv[8];
#pragma unroll
    for (int nt = 0; nt < 8; ++nt) {
        bfr[nt] = *(const short8*)(Wtr + (nt * 16 + col) * 32 + quad * 8);
        rbv[nt] = resb[nt * 16 + col];
    }
    short8 afr[2];
#pragma unroll
    for (int mt = 0; mt < 2; ++mt) {
        int r = m0 + wv * 32 + mt * 16 + col;
        if (r > 15359) r = 15359;
        afr[mt] = *(const short8*)(Pb + (long)r * 24 + quad * 8);
    }
    f32x4 acc[2][8];
#pragma unroll
    for (int i = 0; i < 2; ++i)
#pragma unroll
        for (int j = 0; j < 8; ++j) acc[i][j] = (f32x4){0.f, 0.f, 0.f, 0.f};
#pragma unroll
    for (int nt = 0; nt < 8; ++nt) {
        acc[0][nt] = __builtin_amdgcn_mfma_f32_16x16x32_bf16(afr[0], bfr[nt], acc[0][nt], 0, 0, 0);
        acc[1][nt] = __builtin_amdgcn_mfma_f32_16x16x32_bf16(afr[1], bfr[nt], acc[1][nt], 0, 0, 0);
    }
#pragma unroll
    for (int mt = 0; mt < 2; ++mt)
#pragma unroll
        for (int nt = 0; nt < 8; ++nt)
#pragma unroll
            for (int rr = 0; rr < 4; ++rr) {
                int lrow = wv * 32 + mt * 16 + quad * 4 + rr;
                ACCs[lrow * 136 + nt * 16 + col] = f2bf(fmaxf(acc[mt][nt][rr] + rbv[nt], 0.f));
            }
    __syncthreads();

    f32x4 acc2[2][8];
#pragma unroll
    for (int i = 0; i < 2; ++i)
#pragma unroll
        for (int j = 0; j < 8; ++j) acc2[i][j] = (f32x4){0.f, 0.f, 0.f, 0.f};
#pragma unroll
    for (int ks = 0; ks < 4; ++ks) {
        short8 am[2];
#pragma unroll
        for (int mt = 0; mt < 2; ++mt)
            am[mt] = *(const short8*)&ACCs[(wv * 32 + mt * 16 + col) * 136 + ks * 32 + quad * 8];
#pragma unroll
        for (int nt = 0; nt < 8; ++nt) {
            short8 bb = *(const short8*)&W1s[(nt * 16 + col) * 136 + ks * 32 + quad * 8];
            acc2[0][nt] = __builtin_amdgcn_mfma_f32_16x16x32_bf16(am[0], bb, acc2[0][nt], 0, 0, 0);
            acc2[1][nt] = __builtin_amdgcn_mfma_f32_16x16x32_bf16(am[1], bb, acc2[1][nt], 0, 0, 0);
        }
    }
#pragma unroll
    for (int mt = 0; mt < 2; ++mt)
#pragma unroll
        for (int nt = 0; nt < 8; ++nt)
#pragma unroll
            for (int rr = 0; rr < 4; ++rr) {
                int t = m0 + wv * 32 + mt * 16 + quad * 4 + rr;
                float v = fmaxf(acc2[mt][nt][rr] + biasL[nt * 16 + col], 0.f);
                A1[((long)b * 15360 + t) * 256 + n0 + nt * 16 + col] = f2bf(v);
            }
}

// ---------------------------------------------------------------------------
__global__ __launch_bounds__(256) void f2_softmax_v2(
    const u16* __restrict__ A, const u16* __restrict__ Wt2,
    const float* __restrict__ bias, float* __restrict__ out)
{
    __shared__ __align__(16) u16 Bs[2][256 * 40];
    __shared__ float biasL[256];
    const int tid = threadIdx.x;
    const int b = blockIdx.y;
    const int t0 = blockIdx.x * 64;
    biasL[tid] = bias[tid];

    const int wv = tid >> 6, lane = tid & 63, col = lane & 15, quad = lane >> 4;
    const u16* Ab = A + (long)b * (15360L * 256);
    const int row = t0 + wv * 16 + col;

    auto stage = [&](int kc, int buf) {
#pragma unroll
        for (int j = 0; j < 4; ++j) {
            int idx = tid * 4 + j;
            int rn = idx >> 2, kk = idx & 3;
            *(uint4*)&Bs[buf][rn * 40 + kk * 8] =
                *(const uint4*)(Wt2 + (long)rn * 256 + kc * 32 + kk * 8);
        }
    };

    short8 afr[8];
#pragma unroll
    for (int kc = 0; kc < 8; ++kc)
        afr[kc] = *(const short8*)(Ab + (long)row * 256 + kc * 32 + quad * 8);

    f32x4 acc[16];
#pragma unroll
    for (int i = 0; i < 16; ++i) acc[i] = (f32x4){0.f, 0.f, 0.f, 0.f};

    stage(0, 0);
    __syncthreads();
    for (int kc = 0; kc < 8; ++kc) {
        int buf = kc & 1;
        if (kc < 7) stage(kc + 1, buf ^ 1);
#pragma unroll
        for (int nt = 0; nt < 16; ++nt) {
            short8 bb = *(const short8*)&Bs[buf][(nt * 16 + col) * 40 + quad * 8];
            acc[nt] = __builtin_amdgcn_mfma_f32_16x16x32_bf16(afr[kc], bb, acc[nt], 0, 0, 0);
        }
        __syncthreads();
    }

#pragma unroll
    for (int r = 0; r < 4; ++r) {
        int tl = wv * 16 + quad * 4 + r;
        float v[16];
        float m = -1e30f;
#pragma unroll
        for (int nt = 0; nt < 16; ++nt) {
            v[nt] = acc[nt][r] + biasL[nt * 16 + col];
            m = fmaxf(m, v[nt]);
        }
        m = fmaxf(m, __shfl_xor(m, 1));
        m = fmaxf(m, __shfl_xor(m, 2));
        m = fmaxf(m, __shfl_xor(m, 4));
        m = fmaxf(m, __shfl_xor(m, 8));
        float s = 0.f;
#pragma unroll
        for (int nt = 0; nt < 16; ++nt) { v[nt] = __expf(v[nt] - m); s += v[nt]; }
        s += __shfl_xor(s, 1);
        s += __shfl_xor(s, 2);
        s += __shfl_xor(s, 4);
        s += __shfl_xor(s, 8);
        float inv = 1.f / s;
        float* op = out + ((long)b * 15360 + t0 + tl) * 256;
#pragma unroll
        for (int nt = 0; nt < 16; ++nt) op[nt * 16 + col] = v[nt] * inv;
    }
}

// ---------------------------------------------------------------------------
extern "C" void kernel_launch(void* const* d_in, const int* in_sizes, int n_in,
                              void* d_out, int out_size, void* d_ws, size_t ws_size,
                              hipStream_t stream)
{
    const float* x        = (const float*)d_in[0];
    const float* causal_W = (const float*)d_in[1];
    const float* causal_b = (const float*)d_in[2];
    const float* gW0      = (const float*)d_in[3];
    const float* gb0      = (const float*)d_in[4];
    const float* fW0      = (const float*)d_in[5];
    const float* fb0      = (const float*)d_in[6];
    const float* sW0      = (const float*)d_in[7];
    const float* sb0      = (const float*)d_in[8];
    const float* gate_W   = (const float*)d_in[9];
    const float* gate_b   = (const float*)d_in[10];
    const float* filter_W = (const float*)d_in[11];
    const float* filter_b = (const float*)d_in[12];
    const float* scale_W  = (const float*)d_in[13];
    const float* scale_b  = (const float*)d_in[14];
    const float* res_W    = (const float*)d_in[15];
    const float* res_b    = (const float*)d_in[16];
    const float* f1_W     = (const float*)d_in[17];
    const float* f1_b     = (const float*)d_in[18];
    const float* f2_W     = (const float*)d_in[19];
    const float* f2_b     = (const float*)d_in[20];

    char* w = (char*)d_ws;
    u16* A1   = (u16*)w;   w += (size_t)8 * 15360 * 256 * 2;
    u16* P0   = (u16*)w;   w += (size_t)8 * 16382 * 24 * 2 + 128;
    u16* P1   = (u16*)w;   w += (size_t)8 * 16382 * 24 * 2 + 128;
    u16* WtGF = (u16*)w;   w += (size_t)64 * 768 * 2;
    u16* Wt1  = (u16*)w;   w += (size_t)256 * 128 * 2;
    u16* Wt2  = (u16*)w;   w += (size_t)256 * 256 * 2;
    u16* Wtr  = (u16*)w;   w += (size_t)128 * 32 * 2;
    float* biasGF = (float*)w; w += 256;
    u16* WgfG = (u16*)w;   w += (size_t)9 * 48 * 64 * 2;
    u16* WsG  = (u16*)w;   w += (size_t)10 * 32 * 32 * 2;

    dim3 blk(256);

    build_all<<<dim3(740), blk, 0, stream>>>(
        causal_W, causal_b, gW0, gb0, fW0, fb0, WtGF, biasGF,
        f1_W, f2_W, res_W + (size_t)8 * 24 * 128,
        gate_W, filter_W, scale_W, sW0,
        Wt1, Wt2, Wtr, WgfG, WsG);

    gf_fused_v8<<<dim3(256, 1, 8), blk, 0, stream>>>(
        x, WtGF, biasGF, WsG + (size_t)9 * 1024, sb0, P0);

    u16* Pprev = P0;
    u16* Pnext = P1;
    int Lprev = 16382;
    for (int i = 0; i < 9; ++i) {
        int d = 2 << i;
        int L = Lprev - d;
        int trim = (i == 8) ? d / 2 : -1;
        gated_mfma_v3<<<dim3((L + 127) / 128, 1, 8), blk, 0, stream>>>(
            Pprev, WgfG + (size_t)i * 3072, WsG + (size_t)i * 1024,
            gate_b + i * 24, filter_b + i * 24, scale_b + i * 24,
            Pnext, L, d, trim);
        u16* tmp = Pprev; Pprev = Pnext; Pnext = tmp;
        Lprev = L;
    }

    res_f1_fused<<<dim3(120, 2, 8), blk, 0, stream>>>(
        Pprev, Wtr, res_b + 8 * 128, Wt1, f1_b, A1);

    f2_softmax_v2<<<dim3(240, 8), blk, 0, stream>>>(A1, Wt2, f2_b, (float*)d_out);
}